// Round 1
// baseline (3921.857 us; speedup 1.0000x reference)
//
#include <hip/hip_runtime.h>
#include <math.h>

// Problem constants
#define NN   1024
#define CS   384
#define CZ   128
#define CH   16
#define HH   12
#define PQK  4
#define PV   8
#define HCH  192      // H*CH
#define HKV  384      // H*2*CH
#define QPR  144      // H*PQK*3
#define KVPR 432      // H*(PQK+PV)*3
#define DCAT 2112     // H*(CZ+CH+PV*4)
#define INF_ 100000.0f

// scales
#define SC_QK   0.14433756729740643f   // sqrt(1/48)
#define SC_B    0.5773502691896258f    // sqrt(1/3)
#define SC_PT   0.13608276348795434f   // sqrt(1/54)

// ---------------------------------------------------------------------------
// Kernel 1: generic small projection GEMM  out[n,c] = s[n,:]@w[:,c] + b[c]
// grid.x = 128 (8 rows each), block = 256
// ---------------------------------------------------------------------------
__global__ __launch_bounds__(256) void proj_gemm(
    const float* __restrict__ s, const float* __restrict__ w,
    const float* __restrict__ b, float* __restrict__ out, int OUT)
{
  __shared__ float s_lds[8 * CS];
  const int n0 = blockIdx.x * 8;
  for (int idx = threadIdx.x; idx < 8 * CS; idx += 256)
    s_lds[idx] = s[(n0 + idx / CS) * CS + (idx % CS)];
  __syncthreads();
  for (int c = threadIdx.x; c < OUT; c += 256) {
    float acc[8];
#pragma unroll
    for (int r = 0; r < 8; r++) acc[r] = 0.f;
    for (int k = 0; k < CS; k++) {
      float wv = w[k * OUT + c];
#pragma unroll
      for (int r = 0; r < 8; r++) acc[r] += s_lds[r * CS + k] * wv;
    }
    float bv = b[c];
#pragma unroll
    for (int r = 0; r < 8; r++) out[(n0 + r) * OUT + c] = acc[r] + bv;
  }
}

// ---------------------------------------------------------------------------
// Kernel 2: split kv, build rotated/translated points, compute qn/kn
// grid = 1024 (one per n), block = 256
// ---------------------------------------------------------------------------
__global__ __launch_bounds__(256) void ipa_transform(
    const float* __restrict__ kv_raw, const float* __restrict__ qp_raw,
    const float* __restrict__ kvp_raw, const float* __restrict__ rot,
    const float* __restrict__ trans,
    float* __restrict__ k, float* __restrict__ v,
    float* __restrict__ q_pts, float* __restrict__ k_pts,
    float* __restrict__ v_pts, float* __restrict__ qn, float* __restrict__ kn)
{
  const int n = blockIdx.x, tid = threadIdx.x;
  __shared__ float R[9], T[3], sq_q[48], sq_k[48];
  if (tid < 9) R[tid] = rot[n * 9 + tid];
  if (tid < 3) T[tid] = trans[n * 3 + tid];
  __syncthreads();
  if (tid < HCH) {
    int h = tid >> 4, c = tid & 15;
    k[n * HCH + tid] = kv_raw[n * HKV + h * 32 + c];
    v[n * HCH + tid] = kv_raw[n * HKV + h * 32 + 16 + c];
  }
  if (tid < 48) {  // q points: hp = tid = h*4+p
    float r0 = qp_raw[n * QPR + tid];
    float r1 = qp_raw[n * QPR + 48 + tid];
    float r2 = qp_raw[n * QPR + 96 + tid];
    float x = R[0] * r0 + R[1] * r1 + R[2] * r2 + T[0];
    float y = R[3] * r0 + R[4] * r1 + R[5] * r2 + T[1];
    float z = R[6] * r0 + R[7] * r1 + R[8] * r2 + T[2];
    q_pts[n * QPR + tid * 3 + 0] = x;
    q_pts[n * QPR + tid * 3 + 1] = y;
    q_pts[n * QPR + tid * 3 + 2] = z;
    sq_q[tid] = x * x + y * y + z * z;
  }
  if (tid >= 64 && tid < 208) {  // kv points: t = h*12+pp
    int t = tid - 64;
    float r0 = kvp_raw[n * KVPR + t];
    float r1 = kvp_raw[n * KVPR + 144 + t];
    float r2 = kvp_raw[n * KVPR + 288 + t];
    float x = R[0] * r0 + R[1] * r1 + R[2] * r2 + T[0];
    float y = R[3] * r0 + R[4] * r1 + R[5] * r2 + T[1];
    float z = R[6] * r0 + R[7] * r1 + R[8] * r2 + T[2];
    int h = t / 12, pp = t % 12;
    if (pp < PQK) {
      int base = n * QPR + (h * 4 + pp) * 3;
      k_pts[base] = x; k_pts[base + 1] = y; k_pts[base + 2] = z;
      sq_k[h * 4 + pp] = x * x + y * y + z * z;
    } else {
      int base = n * (HH * PV * 3) + (h * 8 + pp - 4) * 3;
      v_pts[base] = x; v_pts[base + 1] = y; v_pts[base + 2] = z;
    }
  }
  __syncthreads();
  if (tid < HH) {
    float a = 0.f, b = 0.f;
#pragma unroll
    for (int p = 0; p < 4; p++) { a += sq_q[tid * 4 + p]; b += sq_k[tid * 4 + p]; }
    qn[n * HH + tid] = a;
    kn[n * HH + tid] = b;
  }
}

// ---------------------------------------------------------------------------
// Kernel 3: fused flash-style IPA core. One block per row i.
// Online softmax over j tiles (TJ=64); z read exactly once from HBM.
// Writes cat[i, 0:2112].
// ---------------------------------------------------------------------------
#define TJ 64
__global__ __launch_bounds__(256) void ipa_flash(
    const float* __restrict__ z, const float* __restrict__ mask,
    const float* __restrict__ wb, const float* __restrict__ bb,
    const float* __restrict__ head_w,
    const float* __restrict__ rot, const float* __restrict__ trans,
    const float* __restrict__ q, const float* __restrict__ k,
    const float* __restrict__ v, const float* __restrict__ q_pts,
    const float* __restrict__ k_pts, const float* __restrict__ v_pts,
    const float* __restrict__ qn, const float* __restrict__ kn,
    float* __restrict__ cat)
{
  const int i = blockIdx.x;
  const int tid = threadIdx.x;

  __shared__ float z_s[TJ * 129];         // z tile, padded stride 129
  __shared__ float wb_s[CZ * HH];         // bias weights
  __shared__ float pl[HH * 65];           // logits -> probs, padded stride 65
  __shared__ float q_s[HCH], qpt_s[QPR];
  __shared__ float qn_s[HH], hw_s[HH], bb_s[HH];
  __shared__ float mrun[HH], lrun[HH], f_s[HH];
  __shared__ float R_s[9], T_s[3];
  __shared__ float opt_s[HH * 24];
  __shared__ float mask_i_s;

  for (int t = tid; t < CZ * HH; t += 256) wb_s[t] = wb[t];
  if (tid < HCH) q_s[tid] = q[i * HCH + tid];
  if (tid < QPR) qpt_s[tid] = q_pts[i * QPR + tid];
  if (tid < HH) {
    qn_s[tid] = qn[i * HH + tid];
    bb_s[tid] = bb[tid];
    float x = head_w[tid];
    float sp = (x > 20.f) ? x : log1pf(__expf(x));
    hw_s[tid] = sp * SC_PT;
    mrun[tid] = -INFINITY;
    lrun[tid] = 0.f;
  }
  if (tid < 9) R_s[tid] = rot[i * 9 + tid];
  if (tid < 3) T_s[tid] = trans[i * 3 + tid];
  if (tid == 0) mask_i_s = mask[i];

  // accumulator ownership
  const int c_op = tid & 127, hg6 = (tid >> 7) * 6;     // o_pair: 6 heads each
  const int h_o = tid >> 4, c_o = tid & 15;             // o: valid tid<192
  const int h_pt = tid / 12, idx_pt = tid % 12;         // o_pt: valid tid<144
  const int jl = tid & 63, hgB = tid >> 6;              // logit phase

  float acc_op[6];
#pragma unroll
  for (int u = 0; u < 6; u++) acc_op[u] = 0.f;
  float acc_o = 0.f, acc_p0 = 0.f, acc_p1 = 0.f;

  __syncthreads();
  const float mask_i = mask_i_s;

  for (int jb = 0; jb < NN; jb += TJ) {
    __syncthreads();  // protect z_s / pl from previous iteration readers
    // ---- Phase A: stage z tile (coalesced float4) ----
    for (int t = tid; t < TJ * 32; t += 256) {
      int r = t >> 5, c4 = t & 31;
      const float4 zv = *reinterpret_cast<const float4*>(
          &z[((size_t)(i * NN + jb + r)) * CZ + c4 * 4]);
      float* d = &z_s[r * 129 + c4 * 4];
      d[0] = zv.x; d[1] = zv.y; d[2] = zv.z; d[3] = zv.w;
    }
    __syncthreads();
    // ---- Phase B: logits for (jl, heads hgB, hgB+4, hgB+8) ----
    {
      const int jg = jb + jl;
      const float smask = INF_ * (mask_i * mask[jg] - 1.0f);
      float bd[3] = {0.f, 0.f, 0.f};
      for (int c = 0; c < CZ; c++) {
        float zv = z_s[jl * 129 + c];
#pragma unroll
        for (int u = 0; u < 3; u++) bd[u] += zv * wb_s[c * HH + (hgB + 4 * u)];
      }
#pragma unroll
      for (int u = 0; u < 3; u++) {
        int h = hgB + 4 * u;
        const float* kp = &k[(size_t)jg * HCH + h * 16];
        float d16 = 0.f;
#pragma unroll
        for (int c = 0; c < 16; c++) d16 += q_s[h * 16 + c] * kp[c];
        const float* kpp = &k_pts[(size_t)jg * QPR + h * 12];
        float cr = 0.f;
#pragma unroll
        for (int x = 0; x < 12; x++) cr += qpt_s[h * 12 + x] * kpp[x];
        float sqd = qn_s[h] + kn[(size_t)jg * HH + h] - 2.f * cr;
        float logit = SC_QK * d16 + SC_B * (bd[u] + bb_s[h])
                      - 0.5f * hw_s[h] * sqd + smask;
        pl[h * 65 + jl] = logit;
      }
    }
    __syncthreads();
    // ---- Phase C: per-head online softmax bookkeeping ----
    {
      const int w = tid >> 6, lane = tid & 63;
      for (int u = 0; u < 3; u++) {
        int h = w * 3 + u;
        float lv = pl[h * 65 + lane];
        float tmax = lv;
        for (int off = 32; off; off >>= 1)
          tmax = fmaxf(tmax, __shfl_xor(tmax, off));
        float m_old = mrun[h];
        float m_new = fmaxf(m_old, tmax);
        float p = __expf(lv - m_new);
        pl[h * 65 + lane] = p;
        float psum = p;
        for (int off = 32; off; off >>= 1) psum += __shfl_xor(psum, off);
        if (lane == 0) {
          float f = __expf(m_old - m_new);
          lrun[h] = lrun[h] * f + psum;
          mrun[h] = m_new;
          f_s[h] = f;
        }
      }
    }
    __syncthreads();
    // ---- Phase D: rescale + accumulate ----
    {
#pragma unroll
      for (int u = 0; u < 6; u++) acc_op[u] *= f_s[hg6 + u];
      if (tid < HCH) acc_o *= f_s[h_o];
      if (tid < 144) { acc_p0 *= f_s[h_pt]; acc_p1 *= f_s[h_pt]; }
      for (int j = 0; j < TJ; j++) {
        float zv = z_s[j * 129 + c_op];
#pragma unroll
        for (int u = 0; u < 6; u++) acc_op[u] += pl[(hg6 + u) * 65 + j] * zv;
      }
      if (tid < HCH) {
        for (int j = 0; j < TJ; j++)
          acc_o += pl[h_o * 65 + j] * v[(size_t)(jb + j) * HCH + h_o * 16 + c_o];
      }
      if (tid < 144) {
        for (int j = 0; j < TJ; j++) {
          float p = pl[h_pt * 65 + j];
          const float* vp = &v_pts[(size_t)(jb + j) * (HH * PV * 3) + h_pt * 24];
          acc_p0 += p * vp[idx_pt];
          acc_p1 += p * vp[idx_pt + 12];
        }
      }
    }
  }
  __syncthreads();
  // ---- Epilogue ----
  float* catr = &cat[(size_t)i * DCAT];
  if (tid < HCH) catr[h_o * 16 + c_o] = acc_o / lrun[h_o];
#pragma unroll
  for (int u = 0; u < 6; u++)
    catr[576 + (hg6 + u) * CZ + c_op] = acc_op[u] / lrun[hg6 + u];
  if (tid < 144) {
    opt_s[h_pt * 24 + idx_pt] = acc_p0 / lrun[h_pt];
    opt_s[h_pt * 24 + idx_pt + 12] = acc_p1 / lrun[h_pt];
  }
  __syncthreads();
  if (tid < 96) {  // h = tid/8, p = tid%8: inverse-rotate, norm
    int h = tid >> 3, p = tid & 7;
    float gx = opt_s[h * 24 + p * 3 + 0] - T_s[0];
    float gy = opt_s[h * 24 + p * 3 + 1] - T_s[1];
    float gz = opt_s[h * 24 + p * 3 + 2] - T_s[2];
    float lx = R_s[0] * gx + R_s[3] * gy + R_s[6] * gz;
    float ly = R_s[1] * gx + R_s[4] * gy + R_s[7] * gz;
    float lz = R_s[2] * gx + R_s[5] * gy + R_s[8] * gz;
    catr[192 + 0 * 96 + h * 8 + p] = lx;
    catr[192 + 1 * 96 + h * 8 + p] = ly;
    catr[192 + 2 * 96 + h * 8 + p] = lz;
    catr[480 + h * 8 + p] = sqrtf(lx * lx + ly * ly + lz * lz + 1e-8f);
  }
}

// ---------------------------------------------------------------------------
// Kernel 4: out = cat @ wout + bout   (1024 x 2112 x 384)
// grid = 128 (8 rows each), block = 384 (one col per thread)
// ---------------------------------------------------------------------------
#define KCH 176
__global__ __launch_bounds__(384) void out_gemm(
    const float* __restrict__ cat, const float* __restrict__ wout,
    const float* __restrict__ bout, float* __restrict__ out)
{
  __shared__ float c_lds[8 * KCH];
  const int n0 = blockIdx.x * 8;
  const int c = threadIdx.x;
  float acc[8];
#pragma unroll
  for (int r = 0; r < 8; r++) acc[r] = 0.f;
  for (int kc = 0; kc < DCAT / KCH; kc++) {
    __syncthreads();
    for (int idx = threadIdx.x; idx < 8 * KCH; idx += 384) {
      int r = idx / KCH, kk = idx % KCH;
      c_lds[idx] = cat[(size_t)(n0 + r) * DCAT + kc * KCH + kk];
    }
    __syncthreads();
    for (int kk = 0; kk < KCH; kk++) {
      float wv = wout[(size_t)(kc * KCH + kk) * CS + c];
#pragma unroll
      for (int r = 0; r < 8; r++) acc[r] += c_lds[r * KCH + kk] * wv;
    }
  }
#pragma unroll
  for (int r = 0; r < 8; r++) out[(n0 + r) * CS + c] = acc[r] + bout[c];
}

// ---------------------------------------------------------------------------
extern "C" void kernel_launch(void* const* d_in, const int* in_sizes, int n_in,
                              void* d_out, int out_size, void* d_ws, size_t ws_size,
                              hipStream_t stream) {
  const float* s      = (const float*)d_in[0];
  const float* z      = (const float*)d_in[1];
  const float* rot    = (const float*)d_in[2];
  const float* trans  = (const float*)d_in[3];
  const float* mask   = (const float*)d_in[4];
  const float* wq     = (const float*)d_in[5];
  const float* bq     = (const float*)d_in[6];
  const float* wkv    = (const float*)d_in[7];
  const float* bkv    = (const float*)d_in[8];
  const float* wqp    = (const float*)d_in[9];
  const float* bqp    = (const float*)d_in[10];
  const float* wkvp   = (const float*)d_in[11];
  const float* bkvp   = (const float*)d_in[12];
  const float* wb     = (const float*)d_in[13];
  const float* bb     = (const float*)d_in[14];
  const float* head_w = (const float*)d_in[15];
  const float* wout   = (const float*)d_in[16];
  const float* bout   = (const float*)d_in[17];
  float* out = (float*)d_out;

  // workspace layout (floats)
  float* ws = (float*)d_ws;
  float* q_buf    = ws;                       // 1024*192
  float* kv_raw   = q_buf + NN * HCH;         // 1024*384
  float* qp_raw   = kv_raw + NN * HKV;        // 1024*144
  float* kvp_raw  = qp_raw + NN * QPR;        // 1024*432
  float* k_buf    = kvp_raw + NN * KVPR;      // 1024*192
  float* v_buf    = k_buf + NN * HCH;         // 1024*192
  float* qpts_buf = v_buf + NN * HCH;         // 1024*144
  float* kpts_buf = qpts_buf + NN * QPR;      // 1024*144
  float* vpts_buf = kpts_buf + NN * QPR;      // 1024*288
  float* qn_buf   = vpts_buf + NN * HH * PV * 3; // 1024*12
  float* kn_buf   = qn_buf + NN * HH;         // 1024*12
  float* cat_buf  = kn_buf + NN * HH;         // 1024*2112

  proj_gemm<<<dim3(NN / 8), dim3(256), 0, stream>>>(s, wq, bq, q_buf, HCH);
  proj_gemm<<<dim3(NN / 8), dim3(256), 0, stream>>>(s, wkv, bkv, kv_raw, HKV);
  proj_gemm<<<dim3(NN / 8), dim3(256), 0, stream>>>(s, wqp, bqp, qp_raw, QPR);
  proj_gemm<<<dim3(NN / 8), dim3(256), 0, stream>>>(s, wkvp, bkvp, kvp_raw, KVPR);

  ipa_transform<<<dim3(NN), dim3(256), 0, stream>>>(
      kv_raw, qp_raw, kvp_raw, rot, trans,
      k_buf, v_buf, qpts_buf, kpts_buf, vpts_buf, qn_buf, kn_buf);

  ipa_flash<<<dim3(NN), dim3(256), 0, stream>>>(
      z, mask, wb, bb, head_w, rot, trans,
      q_buf, k_buf, v_buf, qpts_buf, kpts_buf, vpts_buf,
      qn_buf, kn_buf, cat_buf);

  out_gemm<<<dim3(NN / 8), dim3(384), 0, stream>>>(cat_buf, wout, bout, out);
}

// Round 2
// 3811.795 us; speedup vs baseline: 1.0289x; 1.0289x over previous
//
#include <hip/hip_runtime.h>
#include <math.h>

// Problem constants
#define NN   1024
#define CS   384
#define CZ   128
#define HH   12
#define HCH  192
#define QPR  144
#define PVD  288      // H*PV*3
#define DCAT 2112
#define PROJW 1152    // 192+384+144+432
#define INF_ 100000.0f

#define SC_QK 0.14433756729740643f   // sqrt(1/48)
#define SC_B  0.5773502691896258f    // sqrt(1/3)
#define SC_PT 0.13608276348795434f   // sqrt(1/54)

#define TJ 64
#define ZS 132     // z_s float stride (132%4==0, byte stride 528 = 16*33)
#define PS 68      // pl float stride (byte 272 = 16*17)
#define PARTN 2048 // floats per partial record (2040 used)

// ---------------------------------------------------------------------------
// prep: transpose wb -> wb_t[h][c], precompute head weights
// ---------------------------------------------------------------------------
__global__ void prep(const float* __restrict__ wb, const float* __restrict__ head_w,
                     float* __restrict__ wb_t, float* __restrict__ hw)
{
  int t = threadIdx.x;
  for (int idx = t; idx < CZ * HH; idx += 256) {
    int c = idx % CZ, h = idx / CZ;
    wb_t[h * CZ + c] = wb[c * HH + h];
  }
  if (t < HH) {
    float x = head_w[t];
    float sp = (x > 20.f) ? x : log1pf(__expf(x));
    hw[t] = sp * SC_PT;
  }
}

// ---------------------------------------------------------------------------
// proj_all: fused s @ {wq,wkv,wqp,wkvp} + bias -> proj[n][1152]
// grid (128, 9), block 256: 8 rows x 128 cols per block, 1 row x 4 cols/thread
// ---------------------------------------------------------------------------
__global__ __launch_bounds__(256) void proj_all(
    const float* __restrict__ s,
    const float* __restrict__ wq, const float* __restrict__ bq,
    const float* __restrict__ wkv, const float* __restrict__ bkv,
    const float* __restrict__ wqp, const float* __restrict__ bqp,
    const float* __restrict__ wkvp, const float* __restrict__ bkvp,
    float* __restrict__ proj)
{
  __shared__ float s_lds[8 * CS];
  const int n0 = blockIdx.x * 8;
  for (int idx = threadIdx.x; idx < 8 * CS; idx += 256)
    s_lds[idx] = s[(size_t)(n0 + idx / CS) * CS + (idx % CS)];
  __syncthreads();

  const int gc = blockIdx.y * 128 + (threadIdx.x & 31) * 4;
  const int rg = threadIdx.x >> 5;
  const float* wp; const float* bp; int OUT, lc;
  if (gc < 192)      { wp = wq;   bp = bq;   OUT = 192; lc = gc; }
  else if (gc < 576) { wp = wkv;  bp = bkv;  OUT = 384; lc = gc - 192; }
  else if (gc < 720) { wp = wqp;  bp = bqp;  OUT = 144; lc = gc - 576; }
  else               { wp = wkvp; bp = bkvp; OUT = 432; lc = gc - 720; }

  float a0 = 0.f, a1 = 0.f, a2 = 0.f, a3 = 0.f;
  const float* srow = &s_lds[rg * CS];
#pragma unroll 4
  for (int kk = 0; kk < CS; kk++) {
    float sv = srow[kk];
    float4 w4 = *reinterpret_cast<const float4*>(&wp[(size_t)kk * OUT + lc]);
    a0 += sv * w4.x; a1 += sv * w4.y; a2 += sv * w4.z; a3 += sv * w4.w;
  }
  float* o = proj + (size_t)(n0 + rg) * PROJW + gc;
  o[0] = a0 + bp[lc]; o[1] = a1 + bp[lc + 1];
  o[2] = a2 + bp[lc + 2]; o[3] = a3 + bp[lc + 3];
}

// ---------------------------------------------------------------------------
// transform: split kv, rotate/translate points, qn/kn. grid 1024, block 256
// ---------------------------------------------------------------------------
__global__ __launch_bounds__(256) void ipa_transform(
    const float* __restrict__ proj, const float* __restrict__ rot,
    const float* __restrict__ trans,
    float* __restrict__ k, float* __restrict__ v,
    float* __restrict__ q_pts, float* __restrict__ k_pts,
    float* __restrict__ v_pts, float* __restrict__ qn, float* __restrict__ kn)
{
  const int n = blockIdx.x, tid = threadIdx.x;
  const float* pr = proj + (size_t)n * PROJW;
  __shared__ float R[9], T[3], sq_q[48], sq_k[48];
  if (tid < 9) R[tid] = rot[n * 9 + tid];
  if (tid < 3) T[tid] = trans[n * 3 + tid];
  __syncthreads();
  if (tid < HCH) {
    int h = tid >> 4, c = tid & 15;
    k[(size_t)n * HCH + tid] = pr[192 + h * 32 + c];
    v[(size_t)n * HCH + tid] = pr[192 + h * 32 + 16 + c];
  }
  if (tid < 48) {
    float r0 = pr[576 + tid], r1 = pr[576 + 48 + tid], r2 = pr[576 + 96 + tid];
    float x = R[0] * r0 + R[1] * r1 + R[2] * r2 + T[0];
    float y = R[3] * r0 + R[4] * r1 + R[5] * r2 + T[1];
    float z = R[6] * r0 + R[7] * r1 + R[8] * r2 + T[2];
    q_pts[(size_t)n * QPR + tid * 3 + 0] = x;
    q_pts[(size_t)n * QPR + tid * 3 + 1] = y;
    q_pts[(size_t)n * QPR + tid * 3 + 2] = z;
    sq_q[tid] = x * x + y * y + z * z;
  }
  if (tid >= 64 && tid < 208) {
    int t = tid - 64;
    float r0 = pr[720 + t], r1 = pr[720 + 144 + t], r2 = pr[720 + 288 + t];
    float x = R[0] * r0 + R[1] * r1 + R[2] * r2 + T[0];
    float y = R[3] * r0 + R[4] * r1 + R[5] * r2 + T[1];
    float z = R[6] * r0 + R[7] * r1 + R[8] * r2 + T[2];
    int h = t / 12, pp = t % 12;
    if (pp < 4) {
      size_t base = (size_t)n * QPR + (h * 4 + pp) * 3;
      k_pts[base] = x; k_pts[base + 1] = y; k_pts[base + 2] = z;
      sq_k[h * 4 + pp] = x * x + y * y + z * z;
    } else {
      size_t base = (size_t)n * PVD + (h * 8 + pp - 4) * 3;
      v_pts[base] = x; v_pts[base + 1] = y; v_pts[base + 2] = z;
    }
  }
  __syncthreads();
  if (tid < HH) {
    float a = 0.f, b = 0.f;
#pragma unroll
    for (int p = 0; p < 4; p++) { a += sq_q[tid * 4 + p]; b += sq_k[tid * 4 + p]; }
    qn[n * HH + tid] = a;
    kn[n * HH + tid] = b;
  }
}

// ---------------------------------------------------------------------------
// ipa_flash: flash IPA over a j-slice. grid (1024, nsplit), block 256.
// Writes unnormalized partial (m, l, acc_o, acc_op, acc_pt).
// ---------------------------------------------------------------------------
__global__ __launch_bounds__(256, 3) void ipa_flash(
    const float* __restrict__ z, const float* __restrict__ mask,
    const float* __restrict__ wb_t, const float* __restrict__ bb,
    const float* __restrict__ hw, const float* __restrict__ proj,
    const float* __restrict__ k, const float* __restrict__ k_pts,
    const float* __restrict__ v, const float* __restrict__ v_pts,
    const float* __restrict__ qn, const float* __restrict__ kn,
    const float* __restrict__ q_pts,
    float* __restrict__ part, int pstride, int nsplit, int ntiles)
{
  const int i = blockIdx.x, sp = blockIdx.y;
  const int tid = threadIdx.x;

  __shared__ float z_s[TJ * ZS];
  __shared__ float pl[HH * PS];
  __shared__ float q_s[HCH], qpt_s[QPR];
  __shared__ float qn_s[HH], hw_s[HH], bb_s[HH];
  __shared__ float mrun[HH], lrun[HH], f_s[HH];
  __shared__ float mask_i_s;

  if (tid < HCH) q_s[tid] = proj[(size_t)i * PROJW + tid];
  if (tid < QPR) qpt_s[tid] = q_pts[(size_t)i * QPR + tid];
  if (tid < HH) {
    qn_s[tid] = qn[i * HH + tid];
    bb_s[tid] = bb[tid];
    hw_s[tid] = hw[tid];
    mrun[tid] = -1e30f;
    lrun[tid] = 0.f;
  }
  if (tid == 0) mask_i_s = mask[i];

  const int jl = tid & 63;
  const int h0 = __builtin_amdgcn_readfirstlane(tid >> 6);  // phase-B head base
  const int c_op = tid & 127, hg6 = (tid >> 7) * 6;
  const int h_o = tid >> 4;
  const int h_pt = tid / 12, idx_pt = tid % 12;

  float acc_op[6];
#pragma unroll
  for (int u = 0; u < 6; u++) acc_op[u] = 0.f;
  float acc_o = 0.f, acc_p0 = 0.f, acc_p1 = 0.f;

  __syncthreads();
  const float mask_i = mask_i_s;
  const int jb0 = sp * ntiles * TJ;

  for (int t = 0; t < ntiles; t++) {
    const int jb = jb0 + t * TJ;
    __syncthreads();
    // ---- A: stage z tile ----
    for (int r4 = tid; r4 < TJ * 32; r4 += 256) {
      int r = r4 >> 5, c4 = r4 & 31;
      float4 zv = *reinterpret_cast<const float4*>(
          &z[((size_t)(i * NN + jb + r)) * CZ + c4 * 4]);
      *reinterpret_cast<float4*>(&z_s[r * ZS + c4 * 4]) = zv;
    }
    __syncthreads();
    // ---- B: logits (lane jl, heads h0, h0+4, h0+8) ----
    {
      const int jg = jb + jl;
      const float smask = INF_ * (mask_i * mask[jg] - 1.0f);
      float bd0 = 0.f, bd1 = 0.f, bd2 = 0.f;
      const float* wr0 = wb_t + (size_t)h0 * CZ;
      const float* wr1 = wb_t + (size_t)(h0 + 4) * CZ;
      const float* wr2 = wb_t + (size_t)(h0 + 8) * CZ;
      const float* zr = &z_s[jl * ZS];
#pragma unroll 4
      for (int cc = 0; cc < 32; cc++) {
        float4 zq = *reinterpret_cast<const float4*>(&zr[cc * 4]);
        float4 w0 = *reinterpret_cast<const float4*>(&wr0[cc * 4]);
        float4 w1 = *reinterpret_cast<const float4*>(&wr1[cc * 4]);
        float4 w2 = *reinterpret_cast<const float4*>(&wr2[cc * 4]);
        bd0 += zq.x * w0.x + zq.y * w0.y + zq.z * w0.z + zq.w * w0.w;
        bd1 += zq.x * w1.x + zq.y * w1.y + zq.z * w1.z + zq.w * w1.w;
        bd2 += zq.x * w2.x + zq.y * w2.y + zq.z * w2.z + zq.w * w2.w;
      }
      float bds[3] = {bd0, bd1, bd2};
#pragma unroll
      for (int u = 0; u < 3; u++) {
        int h = h0 + 4 * u;
        const float* kp = &k[(size_t)jg * HCH + h * 16];
        float d16 = 0.f;
#pragma unroll
        for (int c = 0; c < 16; c++) d16 += q_s[h * 16 + c] * kp[c];
        const float* kpp = &k_pts[(size_t)jg * QPR + h * 12];
        float cr = 0.f;
#pragma unroll
        for (int x = 0; x < 12; x++) cr += qpt_s[h * 12 + x] * kpp[x];
        float sqd = qn_s[h] + kn[(size_t)jg * HH + h] - 2.f * cr;
        pl[h * PS + jl] = SC_QK * d16 + SC_B * (bds[u] + bb_s[h])
                          - 0.5f * hw_s[h] * sqd + smask;
      }
    }
    __syncthreads();
    // ---- C: online softmax bookkeeping ----
    {
      const int w = tid >> 6, lane = tid & 63;
#pragma unroll
      for (int u = 0; u < 3; u++) {
        int h = w * 3 + u;
        float lv = pl[h * PS + lane];
        float tmax = lv;
        for (int off = 32; off; off >>= 1)
          tmax = fmaxf(tmax, __shfl_xor(tmax, off));
        float m_old = mrun[h];
        float m_new = fmaxf(m_old, tmax);
        float p = __expf(lv - m_new);
        pl[h * PS + lane] = p;
        float psum = p;
        for (int off = 32; off; off >>= 1) psum += __shfl_xor(psum, off);
        if (lane == 0) {
          float f = __expf(m_old - m_new);
          lrun[h] = lrun[h] * f + psum;
          mrun[h] = m_new;
          f_s[h] = f;
        }
      }
    }
    __syncthreads();
    // ---- D: rescale + accumulate ----
    {
#pragma unroll
      for (int u = 0; u < 6; u++) acc_op[u] *= f_s[hg6 + u];
      if (tid < HCH) acc_o *= f_s[h_o];
      if (tid < 144) { acc_p0 *= f_s[h_pt]; acc_p1 *= f_s[h_pt]; }

      // o_pair: all 256 threads
      for (int j4 = 0; j4 < TJ / 4; j4++) {
        float pqa[6][4];
#pragma unroll
        for (int u = 0; u < 6; u++) {
          float4 t4 = *reinterpret_cast<const float4*>(&pl[(hg6 + u) * PS + j4 * 4]);
          pqa[u][0] = t4.x; pqa[u][1] = t4.y; pqa[u][2] = t4.z; pqa[u][3] = t4.w;
        }
#pragma unroll
        for (int d = 0; d < 4; d++) {
          float zv = z_s[(j4 * 4 + d) * ZS + c_op];
#pragma unroll
          for (int u = 0; u < 6; u++) acc_op[u] += pqa[u][d] * zv;
        }
      }
      if (tid < HCH) {
        const float* vp = v + (size_t)jb * HCH + tid;
        const float* plh = &pl[h_o * PS];
#pragma unroll 4
        for (int j = 0; j < TJ; j++) acc_o += plh[j] * vp[(size_t)j * HCH];
      }
      if (tid < 144) {
        const float* vpp = v_pts + (size_t)jb * PVD + h_pt * 24 + idx_pt;
        const float* plh = &pl[h_pt * PS];
#pragma unroll 4
        for (int j = 0; j < TJ; j++) {
          float p = plh[j];
          acc_p0 += p * vpp[(size_t)j * PVD];
          acc_p1 += p * vpp[(size_t)j * PVD + 12];
        }
      }
    }
  }
  __syncthreads();
  // ---- write partial record ----
  float* pp = part + (size_t)(i * nsplit + sp) * pstride;
  if (tid < HH) { pp[tid] = mrun[tid]; pp[12 + tid] = lrun[tid]; }
  if (tid < HCH) pp[24 + tid] = acc_o;
#pragma unroll
  for (int u = 0; u < 6; u++) pp[216 + (hg6 + u) * CZ + c_op] = acc_op[u];
  if (tid < 144) {
    pp[1752 + h_pt * 24 + idx_pt] = acc_p0;
    pp[1752 + h_pt * 24 + idx_pt + 12] = acc_p1;
  }
}

// ---------------------------------------------------------------------------
// ipa_reduce: combine nsplit partials, epilogue (rotation+norm), write cat
// grid 1024, block 256
// ---------------------------------------------------------------------------
__global__ __launch_bounds__(256) void ipa_reduce(
    const float* __restrict__ part, int pstride, int nsplit,
    const float* __restrict__ rot, const float* __restrict__ trans,
    float* __restrict__ cat)
{
  __shared__ float ps[4 * PARTN];
  __shared__ float wsc[4 * HH], Linv[HH];
  __shared__ float opt_s[288], R_s[9], T_s[3];
  const int i = blockIdx.x, tid = threadIdx.x;

  for (int sidx = 0; sidx < nsplit; sidx++)
    for (int idx = tid; idx < 2040; idx += 256)
      ps[sidx * PARTN + idx] = part[(size_t)(i * nsplit + sidx) * pstride + idx];
  if (tid < 9) R_s[tid] = rot[i * 9 + tid];
  if (tid < 3) T_s[tid] = trans[i * 3 + tid];
  __syncthreads();

  if (tid < HH) {
    float M = -1e30f;
    for (int sx = 0; sx < nsplit; sx++) M = fmaxf(M, ps[sx * PARTN + tid]);
    float L = 0.f;
    for (int sx = 0; sx < nsplit; sx++) {
      float w = __expf(ps[sx * PARTN + tid] - M);
      wsc[sx * HH + tid] = w;
      L += w * ps[sx * PARTN + 12 + tid];
    }
    Linv[tid] = 1.f / L;
  }
  __syncthreads();

  float* catr = cat + (size_t)i * DCAT;
  if (tid < HCH) {
    int h = tid >> 4;
    float a = 0.f;
    for (int sx = 0; sx < nsplit; sx++)
      a += ps[sx * PARTN + 24 + tid] * wsc[sx * HH + h];
    catr[tid] = a * Linv[h];
  }
  {
    int c = tid & 127, hg = (tid >> 7) * 6;
#pragma unroll
    for (int u = 0; u < 6; u++) {
      int h = hg + u;
      float a = 0.f;
      for (int sx = 0; sx < nsplit; sx++)
        a += ps[sx * PARTN + 216 + h * CZ + c] * wsc[sx * HH + h];
      catr[576 + h * CZ + c] = a * Linv[h];
    }
  }
  if (tid < 144) {
    int h = tid / 12, ix = tid % 12;
    float a0 = 0.f, a1 = 0.f;
    for (int sx = 0; sx < nsplit; sx++) {
      float w = wsc[sx * HH + h];
      a0 += ps[sx * PARTN + 1752 + h * 24 + ix] * w;
      a1 += ps[sx * PARTN + 1752 + h * 24 + ix + 12] * w;
    }
    opt_s[h * 24 + ix] = a0 * Linv[h];
    opt_s[h * 24 + ix + 12] = a1 * Linv[h];
  }
  __syncthreads();
  if (tid < 96) {
    int h = tid >> 3, p = tid & 7;
    float gx = opt_s[h * 24 + p * 3 + 0] - T_s[0];
    float gy = opt_s[h * 24 + p * 3 + 1] - T_s[1];
    float gz = opt_s[h * 24 + p * 3 + 2] - T_s[2];
    float lx = R_s[0] * gx + R_s[3] * gy + R_s[6] * gz;
    float ly = R_s[1] * gx + R_s[4] * gy + R_s[7] * gz;
    float lz = R_s[2] * gx + R_s[5] * gy + R_s[8] * gz;
    catr[192 + 0 * 96 + h * 8 + p] = lx;
    catr[192 + 1 * 96 + h * 8 + p] = ly;
    catr[192 + 2 * 96 + h * 8 + p] = lz;
    catr[480 + h * 8 + p] = sqrtf(lx * lx + ly * ly + lz * lz + 1e-8f);
  }
}

// ---------------------------------------------------------------------------
// out_gemm: out = cat @ wout + bout  (1024 x 2112 x 384)
// grid (128, 3), block 256: 8 rows x 128 cols per block, 1 row x 4 cols/thread
// ---------------------------------------------------------------------------
#define OKC 352
__global__ __launch_bounds__(256) void out_gemm(
    const float* __restrict__ cat, const float* __restrict__ wout,
    const float* __restrict__ bout, float* __restrict__ out)
{
  __shared__ float c_lds[8 * OKC];
  const int n0 = blockIdx.x * 8;
  const int cq = blockIdx.y * 128 + (threadIdx.x & 31) * 4;
  const int rg = threadIdx.x >> 5;
  float a0 = 0.f, a1 = 0.f, a2 = 0.f, a3 = 0.f;
  for (int kc = 0; kc < DCAT / OKC; kc++) {
    __syncthreads();
    for (int idx = threadIdx.x; idx < 8 * OKC; idx += 256) {
      int r = idx / OKC, kk = idx % OKC;
      c_lds[idx] = cat[(size_t)(n0 + r) * DCAT + kc * OKC + kk];
    }
    __syncthreads();
    const float* crow = &c_lds[rg * OKC];
#pragma unroll 4
    for (int kk = 0; kk < OKC; kk++) {
      float cv = crow[kk];
      float4 w4 = *reinterpret_cast<const float4*>(
          &wout[(size_t)(kc * OKC + kk) * CS + cq]);
      a0 += cv * w4.x; a1 += cv * w4.y; a2 += cv * w4.z; a3 += cv * w4.w;
    }
  }
  float* o = out + (size_t)(n0 + rg) * CS + cq;
  o[0] = a0 + bout[cq]; o[1] = a1 + bout[cq + 1];
  o[2] = a2 + bout[cq + 2]; o[3] = a3 + bout[cq + 3];
}

// ---------------------------------------------------------------------------
extern "C" void kernel_launch(void* const* d_in, const int* in_sizes, int n_in,
                              void* d_out, int out_size, void* d_ws, size_t ws_size,
                              hipStream_t stream) {
  const float* s      = (const float*)d_in[0];
  const float* z      = (const float*)d_in[1];
  const float* rot    = (const float*)d_in[2];
  const float* trans  = (const float*)d_in[3];
  const float* mask   = (const float*)d_in[4];
  const float* wq     = (const float*)d_in[5];
  const float* bq     = (const float*)d_in[6];
  const float* wkv    = (const float*)d_in[7];
  const float* bkv    = (const float*)d_in[8];
  const float* wqp    = (const float*)d_in[9];
  const float* bqp    = (const float*)d_in[10];
  const float* wkvp   = (const float*)d_in[11];
  const float* bkvp   = (const float*)d_in[12];
  const float* wb     = (const float*)d_in[13];
  const float* bb     = (const float*)d_in[14];
  const float* head_w = (const float*)d_in[15];
  const float* wout   = (const float*)d_in[16];
  const float* bout   = (const float*)d_in[17];
  float* out = (float*)d_out;

  // workspace layout (floats)
  float* ws = (float*)d_ws;
  float* proj_buf = ws;                               // 1024*1152
  float* k_buf    = proj_buf + (size_t)NN * PROJW;    // 1024*192
  float* v_buf    = k_buf + (size_t)NN * HCH;         // 1024*192
  float* qpts_buf = v_buf + (size_t)NN * HCH;         // 1024*144
  float* kpts_buf = qpts_buf + (size_t)NN * QPR;      // 1024*144
  float* vpts_buf = kpts_buf + (size_t)NN * QPR;      // 1024*288
  float* qn_buf   = vpts_buf + (size_t)NN * PVD;      // 1024*12
  float* kn_buf   = qn_buf + NN * HH;                 // 1024*12
  float* wbt_buf  = kn_buf + NN * HH;                 // 1536
  float* hw_buf   = wbt_buf + CZ * HH;                // 16
  float* cat_buf  = hw_buf + 16;                      // 1024*2112
  float* part_buf = cat_buf + (size_t)NN * DCAT;      // nsplit*1024*2048

  size_t base_floats = (size_t)(cat_buf - ws) + (size_t)NN * DCAT;
  int nsplit; float* part; int pstride;
  if (ws_size >= (base_floats + 4ull * NN * PARTN) * 4) {
    nsplit = 4; part = part_buf; pstride = PARTN;
  } else if (ws_size >= (base_floats + 2ull * NN * PARTN) * 4) {
    nsplit = 2; part = part_buf; pstride = PARTN;
  } else {
    nsplit = 1; part = cat_buf; pstride = DCAT;  // alias: reduce stages to LDS first
  }
  const int ntiles = (NN / TJ) / nsplit;

  prep<<<dim3(1), dim3(256), 0, stream>>>(wb, head_w, wbt_buf, hw_buf);
  proj_all<<<dim3(NN / 8, 9), dim3(256), 0, stream>>>(
      s, wq, bq, wkv, bkv, wqp, bqp, wkvp, bkvp, proj_buf);
  ipa_transform<<<dim3(NN), dim3(256), 0, stream>>>(
      proj_buf, rot, trans, k_buf, v_buf, qpts_buf, kpts_buf, vpts_buf,
      qn_buf, kn_buf);
  ipa_flash<<<dim3(NN, nsplit), dim3(256), 0, stream>>>(
      z, mask, wbt_buf, bb, hw_buf, proj_buf, k_buf, kpts_buf, v_buf, vpts_buf,
      qn_buf, kn_buf, qpts_buf, part, pstride, nsplit, ntiles);
  ipa_reduce<<<dim3(NN), dim3(256), 0, stream>>>(
      part, pstride, nsplit, rot, trans, cat_buf);
  out_gemm<<<dim3(NN / 8, 3), dim3(256), 0, stream>>>(
      cat_buf, wout, bout, out);
}

// Round 3
// 1321.238 us; speedup vs baseline: 2.9683x; 2.8850x over previous
//
#include <hip/hip_runtime.h>
#include <hip/hip_bf16.h>
#include <math.h>

// Problem constants
#define NN   1024
#define CS   384
#define CZ   128
#define HH   12
#define HCH  192
#define QPR  144
#define DCAT 2112
#define PROJW 1152    // 192+384+144+432
#define INF_ 100000.0f

#define SC_QK 0.14433756729740643f   // sqrt(1/48)
#define SC_B  0.5773502691896258f    // sqrt(1/3)
#define SC_PT 0.13608276348795434f   // sqrt(1/54)

#define ZS 132     // z LDS stride (floats)

__device__ __forceinline__ float dot4(float4 a, float4 b) {
  return a.x * b.x + a.y * b.y + a.z * b.z + a.w * b.w;
}

// ---------------------------------------------------------------------------
// prep: wb_t[h][c] transpose + softplus(head_w) scale
// ---------------------------------------------------------------------------
__global__ void prep(const float* __restrict__ wb, const float* __restrict__ head_w,
                     float* __restrict__ wb_t, float* __restrict__ hw)
{
  int t = threadIdx.x;
  for (int idx = t; idx < CZ * HH; idx += 256) {
    int c = idx % CZ, h = idx / CZ;
    wb_t[h * CZ + c] = wb[c * HH + h];
  }
  if (t < HH) {
    float x = head_w[t];
    float sp = (x > 20.f) ? x : log1pf(__expf(x));
    hw[t] = sp * SC_PT;
  }
}

// ---------------------------------------------------------------------------
// proj_all: fused s @ {wq,wkv,wqp,wkvp} + bias -> proj[n][1152]
// ---------------------------------------------------------------------------
__global__ __launch_bounds__(256) void proj_all(
    const float* __restrict__ s,
    const float* __restrict__ wq, const float* __restrict__ bq,
    const float* __restrict__ wkv, const float* __restrict__ bkv,
    const float* __restrict__ wqp, const float* __restrict__ bqp,
    const float* __restrict__ wkvp, const float* __restrict__ bkvp,
    float* __restrict__ proj)
{
  __shared__ float s_lds[8 * CS];
  const int n0 = blockIdx.x * 8;
  for (int idx = threadIdx.x; idx < 8 * CS; idx += 256)
    s_lds[idx] = s[(size_t)(n0 + idx / CS) * CS + (idx % CS)];
  __syncthreads();

  const int gc = blockIdx.y * 128 + (threadIdx.x & 31) * 4;
  const int rg = threadIdx.x >> 5;
  const float* wp; const float* bp; int OUT, lc;
  if (gc < 192)      { wp = wq;   bp = bq;   OUT = 192; lc = gc; }
  else if (gc < 576) { wp = wkv;  bp = bkv;  OUT = 384; lc = gc - 192; }
  else if (gc < 720) { wp = wqp;  bp = bqp;  OUT = 144; lc = gc - 576; }
  else               { wp = wkvp; bp = bkvp; OUT = 432; lc = gc - 720; }

  float a0 = 0.f, a1 = 0.f, a2 = 0.f, a3 = 0.f;
  const float* srow = &s_lds[rg * CS];
#pragma unroll 4
  for (int kk = 0; kk < CS; kk++) {
    float sv = srow[kk];
    float4 w4 = *reinterpret_cast<const float4*>(&wp[(size_t)kk * OUT + lc]);
    a0 += sv * w4.x; a1 += sv * w4.y; a2 += sv * w4.z; a3 += sv * w4.w;
  }
  float* o = proj + (size_t)(n0 + rg) * PROJW + gc;
  o[0] = a0 + bp[lc]; o[1] = a1 + bp[lc + 1];
  o[2] = a2 + bp[lc + 2]; o[3] = a3 + bp[lc + 3];
}

// ---------------------------------------------------------------------------
// transform: split kv, rotate/translate points, write HEAD-MAJOR layouts:
//   k_t[(h*1024+n)*16+c], v_t likewise, kpts_t[(h*1024+n)*12+d],
//   vpts_t[(h*1024+n)*24+d], kn_t[h*1024+n]; q_pts/qn row-major per n.
// ---------------------------------------------------------------------------
__global__ __launch_bounds__(256) void ipa_transform(
    const float* __restrict__ proj, const float* __restrict__ rot,
    const float* __restrict__ trans,
    float* __restrict__ k_t, float* __restrict__ v_t,
    float* __restrict__ q_pts, float* __restrict__ kpts_t,
    float* __restrict__ vpts_t, float* __restrict__ qn, float* __restrict__ kn_t)
{
  const int n = blockIdx.x, tid = threadIdx.x;
  const float* pr = proj + (size_t)n * PROJW;
  __shared__ float R[9], T[3], sq_q[48], sq_k[48];
  if (tid < 9) R[tid] = rot[n * 9 + tid];
  if (tid < 3) T[tid] = trans[n * 3 + tid];
  __syncthreads();
  if (tid < HCH) {
    int h = tid >> 4, c = tid & 15;
    k_t[(size_t)(h * NN + n) * 16 + c] = pr[192 + h * 32 + c];
    v_t[(size_t)(h * NN + n) * 16 + c] = pr[192 + h * 32 + 16 + c];
  }
  if (tid < 48) {
    float r0 = pr[576 + tid], r1 = pr[576 + 48 + tid], r2 = pr[576 + 96 + tid];
    float x = R[0] * r0 + R[1] * r1 + R[2] * r2 + T[0];
    float y = R[3] * r0 + R[4] * r1 + R[5] * r2 + T[1];
    float z = R[6] * r0 + R[7] * r1 + R[8] * r2 + T[2];
    q_pts[(size_t)n * QPR + tid * 3 + 0] = x;
    q_pts[(size_t)n * QPR + tid * 3 + 1] = y;
    q_pts[(size_t)n * QPR + tid * 3 + 2] = z;
    sq_q[tid] = x * x + y * y + z * z;
  }
  if (tid >= 64 && tid < 208) {
    int t = tid - 64;
    float r0 = pr[720 + t], r1 = pr[720 + 144 + t], r2 = pr[720 + 288 + t];
    float x = R[0] * r0 + R[1] * r1 + R[2] * r2 + T[0];
    float y = R[3] * r0 + R[4] * r1 + R[5] * r2 + T[1];
    float z = R[6] * r0 + R[7] * r1 + R[8] * r2 + T[2];
    int h = t / 12, pp = t % 12;
    if (pp < 4) {
      size_t base = (size_t)(h * NN + n) * 12 + pp * 3;
      kpts_t[base] = x; kpts_t[base + 1] = y; kpts_t[base + 2] = z;
      sq_k[h * 4 + pp] = x * x + y * y + z * z;
    } else {
      size_t base = (size_t)(h * NN + n) * 24 + (pp - 4) * 3;
      vpts_t[base] = x; vpts_t[base + 1] = y; vpts_t[base + 2] = z;
    }
  }
  __syncthreads();
  if (tid < HH) {
    float a = 0.f, b = 0.f;
#pragma unroll
    for (int p = 0; p < 4; p++) { a += sq_q[tid * 4 + p]; b += sq_k[tid * 4 + p]; }
    qn[n * HH + tid] = a;
    kn_t[tid * NN + n] = b;
  }
}

// ---------------------------------------------------------------------------
// bias_pass: B[i,h,j] = sum_c z[i,j,c] * wb_t[h,c]  (bf16 out, no bb)
// grid (16 jt, 1024 i), block 256. z read exactly once (512 MB).
// ---------------------------------------------------------------------------
__global__ __launch_bounds__(256) void bias_pass(
    const float* __restrict__ z, const float* __restrict__ wb_t,
    __hip_bfloat16* __restrict__ B)
{
  __shared__ float z_s[64 * ZS];
  __shared__ float wb_s[HH * CZ];
  __shared__ float bias_s[HH * 64];
  const int i = blockIdx.y, jb = blockIdx.x * 64;
  const int tid = threadIdx.x;

  for (int e = tid; e < HH * CZ; e += 256) wb_s[e] = wb_t[e];
  for (int e = tid; e < 64 * 32; e += 256) {
    int r = e >> 5, c4 = e & 31;
    float4 zv = *reinterpret_cast<const float4*>(
        &z[((size_t)i * NN + jb + r) * CZ + c4 * 4]);
    *reinterpret_cast<float4*>(&z_s[r * ZS + c4 * 4]) = zv;
  }
  __syncthreads();

  // thread (j = tid>>2, csub = tid&3); c = csub*4 + k8*16 (conflict-spread)
  const int j = tid >> 2, csub = tid & 3;
  float bd[HH];
#pragma unroll
  for (int h = 0; h < HH; h++) bd[h] = 0.f;
#pragma unroll
  for (int k8 = 0; k8 < 8; k8++) {
    const int c = csub * 4 + k8 * 16;
    float4 zq = *reinterpret_cast<const float4*>(&z_s[j * ZS + c]);
#pragma unroll
    for (int h = 0; h < HH; h++) {
      float4 wq = *reinterpret_cast<const float4*>(&wb_s[h * CZ + c]);
      bd[h] += dot4(zq, wq);
    }
  }
#pragma unroll
  for (int h = 0; h < HH; h++) {
    bd[h] += __shfl_xor(bd[h], 1);
    bd[h] += __shfl_xor(bd[h], 2);
    if (csub == 0) bias_s[h * 64 + j] = bd[h];
  }
  __syncthreads();
  for (int e = tid; e < HH * 64; e += 256) {
    int h = e >> 6, j2 = e & 63;
    B[((size_t)i * HH + h) * NN + jb + j2] = __float2bfloat16(bias_s[e]);
  }
}

// ---------------------------------------------------------------------------
// ipa_attn: full logits + row softmax + o + o_pt (NO z). One block per i.
// Warp w handles heads 3w..3w+2; lane holds 16 j's (j = t*64+lane).
// Writes normalized A (bf16) in place over B; writes cat[0:576].
// ---------------------------------------------------------------------------
__global__ __launch_bounds__(256) void ipa_attn(
    const float* __restrict__ k_t, const float* __restrict__ kpts_t,
    const float* __restrict__ kn_t, const float* __restrict__ v_t,
    const float* __restrict__ vpts_t, const float* __restrict__ proj,
    const float* __restrict__ q_pts, const float* __restrict__ qn,
    const float* __restrict__ bb, const float* __restrict__ hw,
    const float* __restrict__ mask, const float* __restrict__ rot,
    const float* __restrict__ trans,
    __hip_bfloat16* __restrict__ A, float* __restrict__ cat)
{
  const int i = blockIdx.x, tid = threadIdx.x;
  const int w = tid >> 6, lane = tid & 63;
  __shared__ float q_s[HCH], qpt_s[QPR], opt_s[288];
  __shared__ float R_s[9], T_s[3];

  if (tid < HCH) q_s[tid] = proj[(size_t)i * PROJW + tid];
  if (tid < QPR) qpt_s[tid] = q_pts[(size_t)i * QPR + tid];
  if (tid < 9) R_s[tid] = rot[i * 9 + tid];
  if (tid < 3) T_s[tid] = trans[i * 3 + tid];
  __syncthreads();
  const float mask_i = mask[i];

#define R4(v) { v.x += __shfl_xor(v.x, off); v.y += __shfl_xor(v.y, off); \
                v.z += __shfl_xor(v.z, off); v.w += __shfl_xor(v.w, off); }
#define FMA4(acc, a_, vv) { acc.x += (a_) * (vv).x; acc.y += (a_) * (vv).y; \
                            acc.z += (a_) * (vv).z; acc.w += (a_) * (vv).w; }

  for (int u = 0; u < 3; u++) {
    const int h = w * 3 + u;
    const float4 q0 = *reinterpret_cast<const float4*>(&q_s[h * 16]);
    const float4 q1 = *reinterpret_cast<const float4*>(&q_s[h * 16 + 4]);
    const float4 q2 = *reinterpret_cast<const float4*>(&q_s[h * 16 + 8]);
    const float4 q3 = *reinterpret_cast<const float4*>(&q_s[h * 16 + 12]);
    const float4 p0 = *reinterpret_cast<const float4*>(&qpt_s[h * 12]);
    const float4 p1 = *reinterpret_cast<const float4*>(&qpt_s[h * 12 + 4]);
    const float4 p2 = *reinterpret_cast<const float4*>(&qpt_s[h * 12 + 8]);
    const float qnv = qn[i * HH + h];
    const float bbv = bb[h];
    const float hwv = hw[h];
    const size_t arow = (size_t)i * HH + h;

    float av[16];
#pragma unroll
    for (int t = 0; t < 16; t++) {
      const int j = t * 64 + lane;
      const float4* kp = reinterpret_cast<const float4*>(&k_t[(size_t)(h * NN + j) * 16]);
      float d16 = dot4(q0, kp[0]) + dot4(q1, kp[1]) + dot4(q2, kp[2]) + dot4(q3, kp[3]);
      const float4* pp = reinterpret_cast<const float4*>(&kpts_t[(size_t)(h * NN + j) * 12]);
      float cross = dot4(p0, pp[0]) + dot4(p1, pp[1]) + dot4(p2, pp[2]);
      float knv = kn_t[h * NN + j];
      float bias = __bfloat162float(A[arow * NN + j]);
      float mj = mask[j];
      av[t] = SC_QK * d16 + SC_B * (bias + bbv)
              - 0.5f * hwv * (qnv + knv - 2.f * cross)
              + INF_ * (mask_i * mj - 1.f);
    }
    // row softmax (1024 elements: 16 regs x 64 lanes)
    float m = av[0];
#pragma unroll
    for (int t = 1; t < 16; t++) m = fmaxf(m, av[t]);
    for (int off = 32; off; off >>= 1) m = fmaxf(m, __shfl_xor(m, off));
    float ssum = 0.f;
#pragma unroll
    for (int t = 0; t < 16; t++) { av[t] = __expf(av[t] - m); ssum += av[t]; }
    for (int off = 32; off; off >>= 1) ssum += __shfl_xor(ssum, off);
    const float inv = 1.f / ssum;
#pragma unroll
    for (int t = 0; t < 16; t++) {
      av[t] *= inv;
      A[arow * NN + t * 64 + lane] = __float2bfloat16(av[t]);
    }
    // o / o_pt accumulation
    float4 o0 = {0,0,0,0}, o1 = {0,0,0,0}, o2 = {0,0,0,0}, o3 = {0,0,0,0};
    float4 w0 = {0,0,0,0}, w1 = {0,0,0,0}, w2 = {0,0,0,0};
    float4 w3 = {0,0,0,0}, w4 = {0,0,0,0}, w5 = {0,0,0,0};
#pragma unroll
    for (int t = 0; t < 16; t++) {
      const int j = t * 64 + lane;
      const float a_ = av[t];
      const float4* vp = reinterpret_cast<const float4*>(&v_t[(size_t)(h * NN + j) * 16]);
      FMA4(o0, a_, vp[0]); FMA4(o1, a_, vp[1]);
      FMA4(o2, a_, vp[2]); FMA4(o3, a_, vp[3]);
      const float4* wp = reinterpret_cast<const float4*>(&vpts_t[(size_t)(h * NN + j) * 24]);
      FMA4(w0, a_, wp[0]); FMA4(w1, a_, wp[1]); FMA4(w2, a_, wp[2]);
      FMA4(w3, a_, wp[3]); FMA4(w4, a_, wp[4]); FMA4(w5, a_, wp[5]);
    }
    for (int off = 32; off; off >>= 1) {
      R4(o0) R4(o1) R4(o2) R4(o3)
      R4(w0) R4(w1) R4(w2) R4(w3) R4(w4) R4(w5)
    }
    if (lane == 0) {
      float* cr = cat + (size_t)i * DCAT + h * 16;
      cr[0] = o0.x; cr[1] = o0.y; cr[2]  = o0.z; cr[3]  = o0.w;
      cr[4] = o1.x; cr[5] = o1.y; cr[6]  = o1.z; cr[7]  = o1.w;
      cr[8] = o2.x; cr[9] = o2.y; cr[10] = o2.z; cr[11] = o2.w;
      cr[12] = o3.x; cr[13] = o3.y; cr[14] = o3.z; cr[15] = o3.w;
      float* os = opt_s + h * 24;
      os[0] = w0.x; os[1] = w0.y; os[2] = w0.z; os[3] = w0.w;
      os[4] = w1.x; os[5] = w1.y; os[6] = w1.z; os[7] = w1.w;
      os[8] = w2.x; os[9] = w2.y; os[10] = w2.z; os[11] = w2.w;
      os[12] = w3.x; os[13] = w3.y; os[14] = w3.z; os[15] = w3.w;
      os[16] = w4.x; os[17] = w4.y; os[18] = w4.z; os[19] = w4.w;
      os[20] = w5.x; os[21] = w5.y; os[22] = w5.z; os[23] = w5.w;
    }
  }
#undef R4
#undef FMA4
  __syncthreads();
  if (tid < 96) {  // inverse rotation + norm
    int h = tid >> 3, p = tid & 7;
    float gx = opt_s[h * 24 + p * 3 + 0] - T_s[0];
    float gy = opt_s[h * 24 + p * 3 + 1] - T_s[1];
    float gz = opt_s[h * 24 + p * 3 + 2] - T_s[2];
    float lx = R_s[0] * gx + R_s[3] * gy + R_s[6] * gz;
    float ly = R_s[1] * gx + R_s[4] * gy + R_s[7] * gz;
    float lz = R_s[2] * gx + R_s[5] * gy + R_s[8] * gz;
    float* catr = cat + (size_t)i * DCAT;
    catr[192 + 0 * 96 + h * 8 + p] = lx;
    catr[192 + 1 * 96 + h * 8 + p] = ly;
    catr[192 + 2 * 96 + h * 8 + p] = lz;
    catr[480 + h * 8 + p] = sqrtf(lx * lx + ly * ly + lz * lz + 1e-8f);
  }
}

// ---------------------------------------------------------------------------
// opair_pass: o_pair[i,h,c] = sum_j A[i,h,j] * z[i,j,c]. One block per i.
// Thread owns (c4 = (tid&31)*4, jsub = tid>>5): all 12 heads in registers,
// each z float4 read once from LDS. Second (final) z pass: 512 MB.
// ---------------------------------------------------------------------------
__global__ __launch_bounds__(256) void opair_pass(
    const float* __restrict__ z, const __hip_bfloat16* __restrict__ A,
    float* __restrict__ cat)
{
  __shared__ float z_s[64 * ZS];
  __shared__ float A_s[HH * 64];
  __shared__ float red[HH * CZ];
  const int i = blockIdx.x, tid = threadIdx.x;
  const int c4 = (tid & 31) * 4, jsub = tid >> 5;

  for (int e = tid; e < HH * CZ; e += 256) red[e] = 0.f;

  float4 acc[HH];
#pragma unroll
  for (int h = 0; h < HH; h++) acc[h] = make_float4(0.f, 0.f, 0.f, 0.f);

  for (int tt = 0; tt < 16; tt++) {
    const int jb = tt * 64;
    __syncthreads();
    for (int e = tid; e < 64 * 32; e += 256) {
      int r = e >> 5, cc = e & 31;
      float4 zv = *reinterpret_cast<const float4*>(
          &z[((size_t)i * NN + jb + r) * CZ + cc * 4]);
      *reinterpret_cast<float4*>(&z_s[r * ZS + cc * 4]) = zv;
    }
    for (int e = tid; e < HH * 64; e += 256) {
      int h = e >> 6, j2 = e & 63;
      A_s[e] = __bfloat162float(A[((size_t)i * HH + h) * NN + jb + j2]);
    }
    __syncthreads();
#pragma unroll
    for (int jj = 0; jj < 8; jj++) {
      const int j = jsub * 8 + jj;
      float4 zq = *reinterpret_cast<const float4*>(&z_s[j * ZS + c4]);
#pragma unroll
      for (int h = 0; h < HH; h++) {
        float a_ = A_s[h * 64 + j];
        acc[h].x += a_ * zq.x; acc[h].y += a_ * zq.y;
        acc[h].z += a_ * zq.z; acc[h].w += a_ * zq.w;
      }
    }
  }
  // cross-jsub reduction in LDS (8 steps, barrier-separated)
  for (int s = 0; s < 8; s++) {
    __syncthreads();
    if (jsub == s) {
#pragma unroll
      for (int h = 0; h < HH; h++) {
        red[h * CZ + c4 + 0] += acc[h].x;
        red[h * CZ + c4 + 1] += acc[h].y;
        red[h * CZ + c4 + 2] += acc[h].z;
        red[h * CZ + c4 + 3] += acc[h].w;
      }
    }
  }
  __syncthreads();
  for (int e = tid; e < HH * CZ; e += 256)
    cat[(size_t)i * DCAT + 576 + e] = red[e];
}

// ---------------------------------------------------------------------------
// out_gemm: out = cat @ wout + bout  (1024 x 2112 x 384)
// ---------------------------------------------------------------------------
#define OKC 352
__global__ __launch_bounds__(256) void out_gemm(
    const float* __restrict__ cat, const float* __restrict__ wout,
    const float* __restrict__ bout, float* __restrict__ out)
{
  __shared__ float c_lds[8 * OKC];
  const int n0 = blockIdx.x * 8;
  const int cq = blockIdx.y * 128 + (threadIdx.x & 31) * 4;
  const int rg = threadIdx.x >> 5;
  float a0 = 0.f, a1 = 0.f, a2 = 0.f, a3 = 0.f;
  for (int kc = 0; kc < DCAT / OKC; kc++) {
    __syncthreads();
    for (int idx = threadIdx.x; idx < 8 * OKC; idx += 256) {
      int r = idx / OKC, kk = idx % OKC;
      c_lds[idx] = cat[(size_t)(n0 + r) * DCAT + kc * OKC + kk];
    }
    __syncthreads();
    const float* crow = &c_lds[rg * OKC];
#pragma unroll 4
    for (int kk = 0; kk < OKC; kk++) {
      float cv = crow[kk];
      float4 w4 = *reinterpret_cast<const float4*>(
          &wout[(size_t)(kc * OKC + kk) * CS + cq]);
      a0 += cv * w4.x; a1 += cv * w4.y; a2 += cv * w4.z; a3 += cv * w4.w;
    }
  }
  float* o = out + (size_t)(n0 + rg) * CS + cq;
  o[0] = a0 + bout[cq]; o[1] = a1 + bout[cq + 1];
  o[2] = a2 + bout[cq + 2]; o[3] = a3 + bout[cq + 3];
}

// ---------------------------------------------------------------------------
extern "C" void kernel_launch(void* const* d_in, const int* in_sizes, int n_in,
                              void* d_out, int out_size, void* d_ws, size_t ws_size,
                              hipStream_t stream) {
  const float* s      = (const float*)d_in[0];
  const float* z      = (const float*)d_in[1];
  const float* rot    = (const float*)d_in[2];
  const float* trans  = (const float*)d_in[3];
  const float* mask   = (const float*)d_in[4];
  const float* wq     = (const float*)d_in[5];
  const float* bq     = (const float*)d_in[6];
  const float* wkv    = (const float*)d_in[7];
  const float* bkv    = (const float*)d_in[8];
  const float* wqp    = (const float*)d_in[9];
  const float* bqp    = (const float*)d_in[10];
  const float* wkvp   = (const float*)d_in[11];
  const float* bkvp   = (const float*)d_in[12];
  const float* wb     = (const float*)d_in[13];
  const float* bb     = (const float*)d_in[14];
  const float* head_w = (const float*)d_in[15];
  const float* wout   = (const float*)d_in[16];
  const float* bout   = (const float*)d_in[17];
  float* out = (float*)d_out;

  // workspace layout (floats; all bases 16-float aligned)
  float* ws = (float*)d_ws;
  float* proj_buf = ws;                                  // 1,179,648
  float* kt_buf   = proj_buf + (size_t)NN * PROJW;       // 196,608
  float* vt_buf   = kt_buf + (size_t)HH * NN * 16;       // 196,608
  float* kptst_buf= vt_buf + (size_t)HH * NN * 16;       // 147,456
  float* vptst_buf= kptst_buf + (size_t)HH * NN * 12;    // 294,912
  float* knt_buf  = vptst_buf + (size_t)HH * NN * 24;    // 12,288
  float* qpts_buf = knt_buf + (size_t)HH * NN;           // 147,456
  float* qn_buf   = qpts_buf + (size_t)NN * QPR;         // 12,288
  float* wbt_buf  = qn_buf + NN * HH;                    // 1,536
  float* hw_buf   = wbt_buf + HH * CZ;                   // 16
  float* cat_buf  = hw_buf + 16;                         // 2,162,688
  __hip_bfloat16* A_buf =
      (__hip_bfloat16*)(cat_buf + (size_t)NN * DCAT);    // 12,582,912 bf16

  prep<<<dim3(1), dim3(256), 0, stream>>>(wb, head_w, wbt_buf, hw_buf);
  proj_all<<<dim3(NN / 8, 9), dim3(256), 0, stream>>>(
      s, wq, bq, wkv, bkv, wqp, bqp, wkvp, bkvp, proj_buf);
  ipa_transform<<<dim3(NN), dim3(256), 0, stream>>>(
      proj_buf, rot, trans, kt_buf, vt_buf, qpts_buf, kptst_buf, vptst_buf,
      qn_buf, knt_buf);
  bias_pass<<<dim3(16, NN), dim3(256), 0, stream>>>(z, wbt_buf, A_buf);
  ipa_attn<<<dim3(NN), dim3(256), 0, stream>>>(
      kt_buf, kptst_buf, knt_buf, vt_buf, vptst_buf, proj_buf, qpts_buf,
      qn_buf, bb, hw_buf, mask, rot, trans, A_buf, cat_buf);
  opair_pass<<<dim3(NN), dim3(256), 0, stream>>>(z, A_buf, cat_buf);
  out_gemm<<<dim3(NN / 8, 3), dim3(256), 0, stream>>>(
      cat_buf, wout, bout, out);
}

// Round 4
// 1052.702 us; speedup vs baseline: 3.7255x; 1.2551x over previous
//
#include <hip/hip_runtime.h>
#include <hip/hip_bf16.h>
#include <math.h>

// Problem constants
#define NN   1024
#define CS   384
#define CZ   128
#define HH   12
#define HCH  192
#define QPR  144
#define DCAT 2112
#define PROJW 1152    // 192+384+144+432
#define INF_ 100000.0f

#define SC_QK 0.14433756729740643f   // sqrt(1/48)
#define SC_B  0.5773502691896258f    // sqrt(1/3)
#define SC_PT 0.13608276348795434f   // sqrt(1/54)

#define ZS 132     // z LDS stride (floats)

__device__ __forceinline__ float dot4(float4 a, float4 b) {
  return a.x * b.x + a.y * b.y + a.z * b.z + a.w * b.w;
}
__device__ __forceinline__ float bf2f(unsigned short u) {
  unsigned int v = ((unsigned int)u) << 16;
  float f; __builtin_memcpy(&f, &v, 4); return f;
}
__device__ __forceinline__ unsigned short f2bf(float f) {
  __hip_bfloat16 h = __float2bfloat16(f);
  unsigned short u; __builtin_memcpy(&u, &h, 2); return u;
}

// ---------------------------------------------------------------------------
// prep: wb_t[h][c] transpose + softplus(head_w) scale
// ---------------------------------------------------------------------------
__global__ void prep(const float* __restrict__ wb, const float* __restrict__ head_w,
                     float* __restrict__ wb_t, float* __restrict__ hw)
{
  int t = threadIdx.x;
  for (int idx = t; idx < CZ * HH; idx += 256) {
    int c = idx % CZ, h = idx / CZ;
    wb_t[h * CZ + c] = wb[c * HH + h];
  }
  if (t < HH) {
    float x = head_w[t];
    float sp = (x > 20.f) ? x : log1pf(__expf(x));
    hw[t] = sp * SC_PT;
  }
}

// ---------------------------------------------------------------------------
// proj_all: fused s @ {wq,wkv,wqp,wkvp} + bias -> proj[n][1152]
// ---------------------------------------------------------------------------
__global__ __launch_bounds__(256) void proj_all(
    const float* __restrict__ s,
    const float* __restrict__ wq, const float* __restrict__ bq,
    const float* __restrict__ wkv, const float* __restrict__ bkv,
    const float* __restrict__ wqp, const float* __restrict__ bqp,
    const float* __restrict__ wkvp, const float* __restrict__ bkvp,
    float* __restrict__ proj)
{
  __shared__ float s_lds[8 * CS];
  const int n0 = blockIdx.x * 8;
  for (int idx = threadIdx.x; idx < 8 * CS; idx += 256)
    s_lds[idx] = s[(size_t)(n0 + idx / CS) * CS + (idx % CS)];
  __syncthreads();

  const int gc = blockIdx.y * 128 + (threadIdx.x & 31) * 4;
  const int rg = threadIdx.x >> 5;
  const float* wp; const float* bp; int OUT, lc;
  if (gc < 192)      { wp = wq;   bp = bq;   OUT = 192; lc = gc; }
  else if (gc < 576) { wp = wkv;  bp = bkv;  OUT = 384; lc = gc - 192; }
  else if (gc < 720) { wp = wqp;  bp = bqp;  OUT = 144; lc = gc - 576; }
  else               { wp = wkvp; bp = bkvp; OUT = 432; lc = gc - 720; }

  float a0 = 0.f, a1 = 0.f, a2 = 0.f, a3 = 0.f;
  const float* srow = &s_lds[rg * CS];
#pragma unroll 4
  for (int kk = 0; kk < CS; kk++) {
    float sv = srow[kk];
    float4 w4 = *reinterpret_cast<const float4*>(&wp[(size_t)kk * OUT + lc]);
    a0 += sv * w4.x; a1 += sv * w4.y; a2 += sv * w4.z; a3 += sv * w4.w;
  }
  float* o = proj + (size_t)(n0 + rg) * PROJW + gc;
  o[0] = a0 + bp[lc]; o[1] = a1 + bp[lc + 1];
  o[2] = a2 + bp[lc + 2]; o[3] = a3 + bp[lc + 3];
}

// ---------------------------------------------------------------------------
// transform: split kv, rotate/translate points, write COMPONENT-MAJOR layouts:
//   kc[(h*16+c)*NN + n], vc likewise, kpc[(h*12+d)*NN + n],
//   vpc[(h*24+d)*NN + n], knc[h*NN + n]; q_pts/qn row-major per n.
// ---------------------------------------------------------------------------
__global__ __launch_bounds__(256) void ipa_transform(
    const float* __restrict__ proj, const float* __restrict__ rot,
    const float* __restrict__ trans,
    float* __restrict__ kc, float* __restrict__ vc,
    float* __restrict__ q_pts, float* __restrict__ kpc,
    float* __restrict__ vpc, float* __restrict__ qn, float* __restrict__ knc)
{
  const int n = blockIdx.x, tid = threadIdx.x;
  const float* pr = proj + (size_t)n * PROJW;
  __shared__ float R[9], T[3], sq_q[48], sq_k[48];
  if (tid < 9) R[tid] = rot[n * 9 + tid];
  if (tid < 3) T[tid] = trans[n * 3 + tid];
  __syncthreads();
  if (tid < HCH) {
    int h = tid >> 4, c = tid & 15;
    kc[(size_t)(h * 16 + c) * NN + n] = pr[192 + h * 32 + c];
    vc[(size_t)(h * 16 + c) * NN + n] = pr[192 + h * 32 + 16 + c];
  }
  if (tid < 48) {
    float r0 = pr[576 + tid], r1 = pr[576 + 48 + tid], r2 = pr[576 + 96 + tid];
    float x = R[0] * r0 + R[1] * r1 + R[2] * r2 + T[0];
    float y = R[3] * r0 + R[4] * r1 + R[5] * r2 + T[1];
    float z = R[6] * r0 + R[7] * r1 + R[8] * r2 + T[2];
    q_pts[(size_t)n * QPR + tid * 3 + 0] = x;
    q_pts[(size_t)n * QPR + tid * 3 + 1] = y;
    q_pts[(size_t)n * QPR + tid * 3 + 2] = z;
    sq_q[tid] = x * x + y * y + z * z;
  }
  if (tid >= 64 && tid < 208) {
    int t = tid - 64;
    float r0 = pr[720 + t], r1 = pr[720 + 144 + t], r2 = pr[720 + 288 + t];
    float x = R[0] * r0 + R[1] * r1 + R[2] * r2 + T[0];
    float y = R[3] * r0 + R[4] * r1 + R[5] * r2 + T[1];
    float z = R[6] * r0 + R[7] * r1 + R[8] * r2 + T[2];
    int h = t / 12, pp = t % 12;
    if (pp < 4) {
      int d = pp * 3;
      kpc[(size_t)(h * 12 + d + 0) * NN + n] = x;
      kpc[(size_t)(h * 12 + d + 1) * NN + n] = y;
      kpc[(size_t)(h * 12 + d + 2) * NN + n] = z;
      sq_k[h * 4 + pp] = x * x + y * y + z * z;
    } else {
      int d = (pp - 4) * 3;
      vpc[(size_t)(h * 24 + d + 0) * NN + n] = x;
      vpc[(size_t)(h * 24 + d + 1) * NN + n] = y;
      vpc[(size_t)(h * 24 + d + 2) * NN + n] = z;
    }
  }
  __syncthreads();
  if (tid < HH) {
    float a = 0.f, b = 0.f;
#pragma unroll
    for (int p = 0; p < 4; p++) { a += sq_q[tid * 4 + p]; b += sq_k[tid * 4 + p]; }
    qn[n * HH + tid] = a;
    knc[(size_t)tid * NN + n] = b;
  }
}

// ---------------------------------------------------------------------------
// bias_pass: B[i,h,j] = sum_c z[i,j,c] * wb_t[h,c]  (bf16 out, no bb)
// grid (16 jt, 1024 i), block 256. z read exactly once (512 MB).
// ---------------------------------------------------------------------------
__global__ __launch_bounds__(256) void bias_pass(
    const float* __restrict__ z, const float* __restrict__ wb_t,
    __hip_bfloat16* __restrict__ B)
{
  __shared__ float z_s[64 * ZS];
  __shared__ float wb_s[HH * CZ];
  __shared__ float bias_s[HH * 64];
  const int i = blockIdx.y, jb = blockIdx.x * 64;
  const int tid = threadIdx.x;

  for (int e = tid; e < HH * CZ; e += 256) wb_s[e] = wb_t[e];
  for (int e = tid; e < 64 * 32; e += 256) {
    int r = e >> 5, c4 = e & 31;
    float4 zv = *reinterpret_cast<const float4*>(
        &z[((size_t)i * NN + jb + r) * CZ + c4 * 4]);
    *reinterpret_cast<float4*>(&z_s[r * ZS + c4 * 4]) = zv;
  }
  __syncthreads();

  const int j = tid >> 2, csub = tid & 3;
  float bd[HH];
#pragma unroll
  for (int h = 0; h < HH; h++) bd[h] = 0.f;
#pragma unroll
  for (int k8 = 0; k8 < 8; k8++) {
    const int c = csub * 4 + k8 * 16;
    float4 zq = *reinterpret_cast<const float4*>(&z_s[j * ZS + c]);
#pragma unroll
    for (int h = 0; h < HH; h++) {
      float4 wq = *reinterpret_cast<const float4*>(&wb_s[h * CZ + c]);
      bd[h] += dot4(zq, wq);
    }
  }
#pragma unroll
  for (int h = 0; h < HH; h++) {
    bd[h] += __shfl_xor(bd[h], 1);
    bd[h] += __shfl_xor(bd[h], 2);
    if (csub == 0) bias_s[h * 64 + j] = bd[h];
  }
  __syncthreads();
  for (int e = tid; e < HH * 64; e += 256) {
    int h = e >> 6, j2 = e & 63;
    B[((size_t)i * HH + h) * NN + jb + j2] = __float2bfloat16(bias_s[e]);
  }
}

// ---------------------------------------------------------------------------
// ipa_attn: one WARP per (i, h). grid (NN/4, HH), block 256 (4 warps).
// Lane owns j = t*256 + lane*4 (t=0..3): all loads fully coalesced float4.
// Writes normalized A (bf16) in place, o into cat, o_pt (pre-rot) into optb.
// ---------------------------------------------------------------------------
__global__ __launch_bounds__(256) void ipa_attn(
    const float* __restrict__ kc, const float* __restrict__ kpc,
    const float* __restrict__ knc, const float* __restrict__ vc,
    const float* __restrict__ vpc, const float* __restrict__ proj,
    const float* __restrict__ q_pts, const float* __restrict__ qn,
    const float* __restrict__ bb, const float* __restrict__ hw,
    const float* __restrict__ mask,
    __hip_bfloat16* __restrict__ A, float* __restrict__ cat,
    float* __restrict__ optb)
{
  const int h = blockIdx.y;
  const int i = blockIdx.x * 4 + (threadIdx.x >> 6);
  const int lane = threadIdx.x & 63;

  // wave-uniform q / q_pts loads
  const float* qb = proj + (size_t)i * PROJW + h * 16;
  const float4 q0 = *reinterpret_cast<const float4*>(qb);
  const float4 q1 = *reinterpret_cast<const float4*>(qb + 4);
  const float4 q2 = *reinterpret_cast<const float4*>(qb + 8);
  const float4 q3 = *reinterpret_cast<const float4*>(qb + 12);
  const float* pb = q_pts + (size_t)i * QPR + h * 12;
  const float4 p0 = *reinterpret_cast<const float4*>(pb);
  const float4 p1 = *reinterpret_cast<const float4*>(pb + 4);
  const float4 p2 = *reinterpret_cast<const float4*>(pb + 8);
  const float qnv = qn[i * HH + h];
  const float bbv = bb[h];
  const float hwv = hw[h];
  const float mi = mask[i];

  const float* kch  = kc  + (size_t)h * 16 * NN;
  const float* kpch = kpc + (size_t)h * 12 * NN;
  const float* knch = knc + (size_t)h * NN;
  const float* vch  = vc  + (size_t)h * 16 * NN;
  const float* vpch = vpc + (size_t)h * 24 * NN;
  __hip_bfloat16* Arow = A + ((size_t)i * HH + h) * NN;

  float4 av[4];
#pragma unroll
  for (int t = 0; t < 4; t++) {
    const int j = t * 256 + lane * 4;
    float4 d = {0, 0, 0, 0};
#pragma unroll
    for (int c = 0; c < 16; c++) {
      const float qc = (c < 4 ? (&q0.x)[c] : c < 8 ? (&q1.x)[c - 4]
                       : c < 12 ? (&q2.x)[c - 8] : (&q3.x)[c - 12]);
      float4 kv = *reinterpret_cast<const float4*>(&kch[(size_t)c * NN + j]);
      d.x += qc * kv.x; d.y += qc * kv.y; d.z += qc * kv.z; d.w += qc * kv.w;
    }
    float4 cr = {0, 0, 0, 0};
#pragma unroll
    for (int dd = 0; dd < 12; dd++) {
      const float pc = (dd < 4 ? (&p0.x)[dd] : dd < 8 ? (&p1.x)[dd - 4]
                        : (&p2.x)[dd - 8]);
      float4 kv = *reinterpret_cast<const float4*>(&kpch[(size_t)dd * NN + j]);
      cr.x += pc * kv.x; cr.y += pc * kv.y; cr.z += pc * kv.z; cr.w += pc * kv.w;
    }
    float4 kn4 = *reinterpret_cast<const float4*>(&knch[j]);
    ushort4 bu = *reinterpret_cast<const ushort4*>(&Arow[j]);
    float4 m4 = *reinterpret_cast<const float4*>(&mask[j]);
    av[t].x = SC_QK * d.x + SC_B * (bf2f(bu.x) + bbv)
              - 0.5f * hwv * (qnv + kn4.x - 2.f * cr.x) + INF_ * (mi * m4.x - 1.f);
    av[t].y = SC_QK * d.y + SC_B * (bf2f(bu.y) + bbv)
              - 0.5f * hwv * (qnv + kn4.y - 2.f * cr.y) + INF_ * (mi * m4.y - 1.f);
    av[t].z = SC_QK * d.z + SC_B * (bf2f(bu.z) + bbv)
              - 0.5f * hwv * (qnv + kn4.z - 2.f * cr.z) + INF_ * (mi * m4.z - 1.f);
    av[t].w = SC_QK * d.w + SC_B * (bf2f(bu.w) + bbv)
              - 0.5f * hwv * (qnv + kn4.w - 2.f * cr.w) + INF_ * (mi * m4.w - 1.f);
  }

  // row softmax across 16 regs x 64 lanes
  float m = av[0].x;
#pragma unroll
  for (int t = 0; t < 4; t++) {
    m = fmaxf(m, av[t].x); m = fmaxf(m, av[t].y);
    m = fmaxf(m, av[t].z); m = fmaxf(m, av[t].w);
  }
  for (int off = 32; off; off >>= 1) m = fmaxf(m, __shfl_xor(m, off));
  float ssum = 0.f;
#pragma unroll
  for (int t = 0; t < 4; t++) {
    av[t].x = __expf(av[t].x - m); ssum += av[t].x;
    av[t].y = __expf(av[t].y - m); ssum += av[t].y;
    av[t].z = __expf(av[t].z - m); ssum += av[t].z;
    av[t].w = __expf(av[t].w - m); ssum += av[t].w;
  }
  for (int off = 32; off; off >>= 1) ssum += __shfl_xor(ssum, off);
  const float inv = 1.f / ssum;
#pragma unroll
  for (int t = 0; t < 4; t++) {
    const int j = t * 256 + lane * 4;
    av[t].x *= inv; av[t].y *= inv; av[t].z *= inv; av[t].w *= inv;
    ushort4 st;
    st.x = f2bf(av[t].x); st.y = f2bf(av[t].y);
    st.z = f2bf(av[t].z); st.w = f2bf(av[t].w);
    *reinterpret_cast<ushort4*>(&Arow[j]) = st;
  }

  // o / o_pt accumulation (coalesced float4 over j)
  float oacc[16], wacc[24];
#pragma unroll
  for (int c = 0; c < 16; c++) oacc[c] = 0.f;
#pragma unroll
  for (int d = 0; d < 24; d++) wacc[d] = 0.f;
#pragma unroll
  for (int t = 0; t < 4; t++) {
    const int j = t * 256 + lane * 4;
    const float4 a4 = av[t];
#pragma unroll
    for (int c = 0; c < 16; c++) {
      float4 vv = *reinterpret_cast<const float4*>(&vch[(size_t)c * NN + j]);
      oacc[c] += dot4(a4, vv);
    }
#pragma unroll
    for (int d = 0; d < 24; d++) {
      float4 wv = *reinterpret_cast<const float4*>(&vpch[(size_t)d * NN + j]);
      wacc[d] += dot4(a4, wv);
    }
  }
  for (int off = 32; off; off >>= 1) {
#pragma unroll
    for (int c = 0; c < 16; c++) oacc[c] += __shfl_xor(oacc[c], off);
#pragma unroll
    for (int d = 0; d < 24; d++) wacc[d] += __shfl_xor(wacc[d], off);
  }
  if (lane == 0) {
    float* cr = cat + (size_t)i * DCAT + h * 16;
#pragma unroll
    for (int c = 0; c < 16; c++) cr[c] = oacc[c];
    float* ob = optb + ((size_t)i * HH + h) * 24;
#pragma unroll
    for (int d = 0; d < 24; d++) ob[d] = wacc[d];
  }
}

// ---------------------------------------------------------------------------
// ipa_finish: inverse-rotate o_pt, norms -> cat[192:576]. grid NN, block 128.
// ---------------------------------------------------------------------------
__global__ __launch_bounds__(128) void ipa_finish(
    const float* __restrict__ optb, const float* __restrict__ rot,
    const float* __restrict__ trans, float* __restrict__ cat)
{
  const int i = blockIdx.x, tid = threadIdx.x;
  __shared__ float R_s[9], T_s[3];
  if (tid < 9) R_s[tid] = rot[i * 9 + tid];
  if (tid < 3) T_s[tid] = trans[i * 3 + tid];
  __syncthreads();
  if (tid < 96) {
    int h = tid >> 3, p = tid & 7;
    const float* ob = optb + ((size_t)i * HH + h) * 24 + p * 3;
    float gx = ob[0] - T_s[0];
    float gy = ob[1] - T_s[1];
    float gz = ob[2] - T_s[2];
    float lx = R_s[0] * gx + R_s[3] * gy + R_s[6] * gz;
    float ly = R_s[1] * gx + R_s[4] * gy + R_s[7] * gz;
    float lz = R_s[2] * gx + R_s[5] * gy + R_s[8] * gz;
    float* catr = cat + (size_t)i * DCAT;
    catr[192 + 0 * 96 + h * 8 + p] = lx;
    catr[192 + 1 * 96 + h * 8 + p] = ly;
    catr[192 + 2 * 96 + h * 8 + p] = lz;
    catr[480 + h * 8 + p] = sqrtf(lx * lx + ly * ly + lz * lz + 1e-8f);
  }
}

// ---------------------------------------------------------------------------
// opair_pass: o_pair[i,h,c] = sum_j A[i,h,j] * z[i,j,c]. One block per i.
// ---------------------------------------------------------------------------
__global__ __launch_bounds__(256) void opair_pass(
    const float* __restrict__ z, const __hip_bfloat16* __restrict__ A,
    float* __restrict__ cat)
{
  __shared__ float z_s[64 * ZS];
  __shared__ float A_s[HH * 64];
  __shared__ float red[HH * CZ];
  const int i = blockIdx.x, tid = threadIdx.x;
  const int c4 = (tid & 31) * 4, jsub = tid >> 5;

  for (int e = tid; e < HH * CZ; e += 256) red[e] = 0.f;

  float4 acc[HH];
#pragma unroll
  for (int h = 0; h < HH; h++) acc[h] = make_float4(0.f, 0.f, 0.f, 0.f);

  for (int tt = 0; tt < 16; tt++) {
    const int jb = tt * 64;
    __syncthreads();
    for (int e = tid; e < 64 * 32; e += 256) {
      int r = e >> 5, cc = e & 31;
      float4 zv = *reinterpret_cast<const float4*>(
          &z[((size_t)i * NN + jb + r) * CZ + cc * 4]);
      *reinterpret_cast<float4*>(&z_s[r * ZS + cc * 4]) = zv;
    }
    for (int e = tid; e < HH * 64; e += 256) {
      int h = e >> 6, j2 = e & 63;
      A_s[e] = __bfloat162float(A[((size_t)i * HH + h) * NN + jb + j2]);
    }
    __syncthreads();
#pragma unroll
    for (int jj = 0; jj < 8; jj++) {
      const int j = jsub * 8 + jj;
      float4 zq = *reinterpret_cast<const float4*>(&z_s[j * ZS + c4]);
#pragma unroll
      for (int h = 0; h < HH; h++) {
        float a_ = A_s[h * 64 + j];
        acc[h].x += a_ * zq.x; acc[h].y += a_ * zq.y;
        acc[h].z += a_ * zq.z; acc[h].w += a_ * zq.w;
      }
    }
  }
  for (int s = 0; s < 8; s++) {
    __syncthreads();
    if (jsub == s) {
#pragma unroll
      for (int h = 0; h < HH; h++) {
        red[h * CZ + c4 + 0] += acc[h].x;
        red[h * CZ + c4 + 1] += acc[h].y;
        red[h * CZ + c4 + 2] += acc[h].z;
        red[h * CZ + c4 + 3] += acc[h].w;
      }
    }
  }
  __syncthreads();
  for (int e = tid; e < HH * CZ; e += 256)
    cat[(size_t)i * DCAT + 576 + e] = red[e];
}

// ---------------------------------------------------------------------------
// out_gemm: out = cat @ wout + bout  (1024 x 2112 x 384)
// grid (256, 3), block 256: 4 rows x 128 cols; whole cat rows staged in LDS.
// ---------------------------------------------------------------------------
__global__ __launch_bounds__(256) void out_gemm(
    const float* __restrict__ cat, const float* __restrict__ wout,
    const float* __restrict__ bout, float* __restrict__ out)
{
  __shared__ float c_lds[4 * DCAT];
  const int n0 = blockIdx.x * 4;
  const int cq = blockIdx.y * 128 + (threadIdx.x & 63) * 2;
  const int rg = threadIdx.x >> 6;
  for (int idx = threadIdx.x; idx < 4 * DCAT; idx += 256) {
    int r = idx / DCAT, kk = idx - r * DCAT;
    c_lds[idx] = cat[(size_t)(n0 + r) * DCAT + kk];
  }
  __syncthreads();
  float a0 = 0.f, a1 = 0.f;
  const float* crow = &c_lds[rg * DCAT];
#pragma unroll 4
  for (int kk = 0; kk < DCAT; kk++) {
    float cv = crow[kk];
    float2 w2 = *reinterpret_cast<const float2*>(&wout[(size_t)kk * CS + cq]);
    a0 += cv * w2.x; a1 += cv * w2.y;
  }
  float* o = out + (size_t)(n0 + rg) * CS + cq;
  o[0] = a0 + bout[cq]; o[1] = a1 + bout[cq + 1];
}

// ---------------------------------------------------------------------------
extern "C" void kernel_launch(void* const* d_in, const int* in_sizes, int n_in,
                              void* d_out, int out_size, void* d_ws, size_t ws_size,
                              hipStream_t stream) {
  const float* s      = (const float*)d_in[0];
  const float* z      = (const float*)d_in[1];
  const float* rot    = (const float*)d_in[2];
  const float* trans  = (const float*)d_in[3];
  const float* mask   = (const float*)d_in[4];
  const float* wq     = (const float*)d_in[5];
  const float* bq     = (const float*)d_in[6];
  const float* wkv    = (const float*)d_in[7];
  const float* bkv    = (const float*)d_in[8];
  const float* wqp    = (const float*)d_in[9];
  const float* bqp    = (const float*)d_in[10];
  const float* wkvp   = (const float*)d_in[11];
  const float* bkvp   = (const float*)d_in[12];
  const float* wb     = (const float*)d_in[13];
  const float* bb     = (const float*)d_in[14];
  const float* head_w = (const float*)d_in[15];
  const float* wout   = (const float*)d_in[16];
  const float* bout   = (const float*)d_in[17];
  float* out = (float*)d_out;

  // workspace layout (floats; all bases 16-float aligned)
  float* ws = (float*)d_ws;
  float* proj_buf = ws;                                  // 1,179,648
  float* kc_buf   = proj_buf + (size_t)NN * PROJW;       // 196,608
  float* vc_buf   = kc_buf + (size_t)HH * 16 * NN;       // 196,608
  float* kpc_buf  = vc_buf + (size_t)HH * 16 * NN;       // 147,456
  float* vpc_buf  = kpc_buf + (size_t)HH * 12 * NN;      // 294,912
  float* knc_buf  = vpc_buf + (size_t)HH * 24 * NN;      // 12,288
  float* qpts_buf = knc_buf + (size_t)HH * NN;           // 147,456
  float* qn_buf   = qpts_buf + (size_t)NN * QPR;         // 12,288
  float* wbt_buf  = qn_buf + NN * HH;                    // 1,536
  float* hw_buf   = wbt_buf + HH * CZ;                   // 16
  float* optb_buf = hw_buf + 16;                         // 294,912
  float* cat_buf  = optb_buf + (size_t)NN * HH * 24;     // 2,162,688
  __hip_bfloat16* A_buf =
      (__hip_bfloat16*)(cat_buf + (size_t)NN * DCAT);    // 12,582,912 bf16

  prep<<<dim3(1), dim3(256), 0, stream>>>(wb, head_w, wbt_buf, hw_buf);
  proj_all<<<dim3(NN / 8, 9), dim3(256), 0, stream>>>(
      s, wq, bq, wkv, bkv, wqp, bqp, wkvp, bkvp, proj_buf);
  ipa_transform<<<dim3(NN), dim3(256), 0, stream>>>(
      proj_buf, rot, trans, kc_buf, vc_buf, qpts_buf, kpc_buf, vpc_buf,
      qn_buf, knc_buf);
  bias_pass<<<dim3(16, NN), dim3(256), 0, stream>>>(z, wbt_buf, A_buf);
  ipa_attn<<<dim3(NN / 4, HH), dim3(256), 0, stream>>>(
      kc_buf, kpc_buf, knc_buf, vc_buf, vpc_buf, proj_buf, qpts_buf,
      qn_buf, bb, hw_buf, mask, A_buf, cat_buf, optb_buf);
  ipa_finish<<<dim3(NN), dim3(128), 0, stream>>>(optb_buf, rot, trans, cat_buf);
  opair_pass<<<dim3(NN), dim3(256), 0, stream>>>(z, A_buf, cat_buf);
  out_gemm<<<dim3(NN / 4, 3), dim3(256), 0, stream>>>(
      cat_buf, wout, bout, out);
}

// Round 5
// 755.780 us; speedup vs baseline: 5.1891x; 1.3929x over previous
//
#include <hip/hip_runtime.h>
#include <hip/hip_bf16.h>
#include <math.h>

// Problem constants
#define NN   1024
#define CS   384
#define CZ   128
#define HH   12
#define HCH  192
#define QPR  144
#define DCAT 2112
#define PROJW 1152    // 192+384+144+432
#define INF_ 100000.0f

#define SC_QK 0.14433756729740643f   // sqrt(1/48)
#define SC_B  0.5773502691896258f    // sqrt(1/3)
#define SC_PT 0.13608276348795434f   // sqrt(1/54)

__device__ __forceinline__ float dot4(float4 a, float4 b) {
  return a.x * b.x + a.y * b.y + a.z * b.z + a.w * b.w;
}
__device__ __forceinline__ float bf2f(unsigned short u) {
  unsigned int v = ((unsigned int)u) << 16;
  float f; __builtin_memcpy(&f, &v, 4); return f;
}
__device__ __forceinline__ unsigned short f2bf(float f) {
  __hip_bfloat16 h = __float2bfloat16(f);
  unsigned short u; __builtin_memcpy(&u, &h, 2); return u;
}

// ---------------------------------------------------------------------------
// prep: wb_t[h][c] transpose + softplus(head_w) scale
// ---------------------------------------------------------------------------
__global__ void prep(const float* __restrict__ wb, const float* __restrict__ head_w,
                     float* __restrict__ wb_t, float* __restrict__ hw)
{
  int t = threadIdx.x;
  for (int idx = t; idx < CZ * HH; idx += 256) {
    int c = idx % CZ, h = idx / CZ;
    wb_t[h * CZ + c] = wb[c * HH + h];
  }
  if (t < HH) {
    float x = head_w[t];
    float sp = (x > 20.f) ? x : log1pf(__expf(x));
    hw[t] = sp * SC_PT;
  }
}

// ---------------------------------------------------------------------------
// proj_all: fused s @ {wq,wkv,wqp,wkvp} + bias -> proj[n][1152]
// ---------------------------------------------------------------------------
__global__ __launch_bounds__(256) void proj_all(
    const float* __restrict__ s,
    const float* __restrict__ wq, const float* __restrict__ bq,
    const float* __restrict__ wkv, const float* __restrict__ bkv,
    const float* __restrict__ wqp, const float* __restrict__ bqp,
    const float* __restrict__ wkvp, const float* __restrict__ bkvp,
    float* __restrict__ proj)
{
  __shared__ float s_lds[8 * CS];
  const int n0 = blockIdx.x * 8;
  for (int idx = threadIdx.x; idx < 8 * CS; idx += 256)
    s_lds[idx] = s[(size_t)(n0 + idx / CS) * CS + (idx % CS)];
  __syncthreads();

  const int gc = blockIdx.y * 128 + (threadIdx.x & 31) * 4;
  const int rg = threadIdx.x >> 5;
  const float* wp; const float* bp; int OUT, lc;
  if (gc < 192)      { wp = wq;   bp = bq;   OUT = 192; lc = gc; }
  else if (gc < 576) { wp = wkv;  bp = bkv;  OUT = 384; lc = gc - 192; }
  else if (gc < 720) { wp = wqp;  bp = bqp;  OUT = 144; lc = gc - 576; }
  else               { wp = wkvp; bp = bkvp; OUT = 432; lc = gc - 720; }

  float a0 = 0.f, a1 = 0.f, a2 = 0.f, a3 = 0.f;
  const float* srow = &s_lds[rg * CS];
#pragma unroll 4
  for (int kk = 0; kk < CS; kk++) {
    float sv = srow[kk];
    float4 w4 = *reinterpret_cast<const float4*>(&wp[(size_t)kk * OUT + lc]);
    a0 += sv * w4.x; a1 += sv * w4.y; a2 += sv * w4.z; a3 += sv * w4.w;
  }
  float* o = proj + (size_t)(n0 + rg) * PROJW + gc;
  o[0] = a0 + bp[lc]; o[1] = a1 + bp[lc + 1];
  o[2] = a2 + bp[lc + 2]; o[3] = a3 + bp[lc + 3];
}

// ---------------------------------------------------------------------------
// transform: split kv, rotate/translate points, write COMPONENT-MAJOR layouts
// ---------------------------------------------------------------------------
__global__ __launch_bounds__(256) void ipa_transform(
    const float* __restrict__ proj, const float* __restrict__ rot,
    const float* __restrict__ trans,
    float* __restrict__ kc, float* __restrict__ vc,
    float* __restrict__ q_pts, float* __restrict__ kpc,
    float* __restrict__ vpc, float* __restrict__ qn, float* __restrict__ knc)
{
  const int n = blockIdx.x, tid = threadIdx.x;
  const float* pr = proj + (size_t)n * PROJW;
  __shared__ float R[9], T[3], sq_q[48], sq_k[48];
  if (tid < 9) R[tid] = rot[n * 9 + tid];
  if (tid < 3) T[tid] = trans[n * 3 + tid];
  __syncthreads();
  if (tid < HCH) {
    int h = tid >> 4, c = tid & 15;
    kc[(size_t)(h * 16 + c) * NN + n] = pr[192 + h * 32 + c];
    vc[(size_t)(h * 16 + c) * NN + n] = pr[192 + h * 32 + 16 + c];
  }
  if (tid < 48) {
    float r0 = pr[576 + tid], r1 = pr[576 + 48 + tid], r2 = pr[576 + 96 + tid];
    float x = R[0] * r0 + R[1] * r1 + R[2] * r2 + T[0];
    float y = R[3] * r0 + R[4] * r1 + R[5] * r2 + T[1];
    float z = R[6] * r0 + R[7] * r1 + R[8] * r2 + T[2];
    q_pts[(size_t)n * QPR + tid * 3 + 0] = x;
    q_pts[(size_t)n * QPR + tid * 3 + 1] = y;
    q_pts[(size_t)n * QPR + tid * 3 + 2] = z;
    sq_q[tid] = x * x + y * y + z * z;
  }
  if (tid >= 64 && tid < 208) {
    int t = tid - 64;
    float r0 = pr[720 + t], r1 = pr[720 + 144 + t], r2 = pr[720 + 288 + t];
    float x = R[0] * r0 + R[1] * r1 + R[2] * r2 + T[0];
    float y = R[3] * r0 + R[4] * r1 + R[5] * r2 + T[1];
    float z = R[6] * r0 + R[7] * r1 + R[8] * r2 + T[2];
    int h = t / 12, pp = t % 12;
    if (pp < 4) {
      int d = pp * 3;
      kpc[(size_t)(h * 12 + d + 0) * NN + n] = x;
      kpc[(size_t)(h * 12 + d + 1) * NN + n] = y;
      kpc[(size_t)(h * 12 + d + 2) * NN + n] = z;
      sq_k[h * 4 + pp] = x * x + y * y + z * z;
    } else {
      int d = (pp - 4) * 3;
      vpc[(size_t)(h * 24 + d + 0) * NN + n] = x;
      vpc[(size_t)(h * 24 + d + 1) * NN + n] = y;
      vpc[(size_t)(h * 24 + d + 2) * NN + n] = z;
    }
  }
  __syncthreads();
  if (tid < HH) {
    float a = 0.f, b = 0.f;
#pragma unroll
    for (int p = 0; p < 4; p++) { a += sq_q[tid * 4 + p]; b += sq_k[tid * 4 + p]; }
    qn[n * HH + tid] = a;
    knc[(size_t)tid * NN + n] = b;
  }
}

// ---------------------------------------------------------------------------
// bias_pass v2: B[i,h,j] = sum_c z[i,j,c]*wb_t[h,c] (bf16 out).
// grid (4, 1024), block 256. Thread (jl=tid>>2, csub=tid&3) handles 4 rows
// (j = jb + jl + jj*64), reading z float4 DIRECTLY from global (no z LDS,
// no per-tile barriers). wb in LDS (broadcast reads), 4-row amortized.
// ---------------------------------------------------------------------------
__global__ __launch_bounds__(256) void bias_pass(
    const float* __restrict__ z, const float* __restrict__ wb_t,
    __hip_bfloat16* __restrict__ B)
{
  __shared__ float wb_s[HH * CZ];      // 6 KB
  __shared__ float bias_s[HH * 256];   // 12 KB
  const int i = blockIdx.y;
  const int jb = blockIdx.x * 256;
  const int tid = threadIdx.x;
  const int jl = tid >> 2, csub = tid & 3;

  for (int e = tid; e < HH * CZ; e += 256) wb_s[e] = wb_t[e];
  __syncthreads();

  float bd[4][HH];
#pragma unroll
  for (int jj = 0; jj < 4; jj++)
#pragma unroll
    for (int h = 0; h < HH; h++) bd[jj][h] = 0.f;

  const float* zbase = z + ((size_t)i * NN + jb + jl) * CZ + csub * 4;
#pragma unroll
  for (int k8 = 0; k8 < 8; k8++) {
    const int c = csub * 4 + k8 * 16;
    float4 wbv[HH];
#pragma unroll
    for (int h = 0; h < HH; h++)
      wbv[h] = *reinterpret_cast<const float4*>(&wb_s[h * CZ + c]);
#pragma unroll
    for (int jj = 0; jj < 4; jj++) {
      float4 zq = *reinterpret_cast<const float4*>(
          &zbase[(size_t)jj * 64 * CZ + k8 * 16]);
#pragma unroll
      for (int h = 0; h < HH; h++) {
        bd[jj][h] += dot4(zq, wbv[h]);
      }
    }
  }
  // reduce across the 4 csub lanes (lane bits 0-1)
#pragma unroll
  for (int jj = 0; jj < 4; jj++)
#pragma unroll
    for (int h = 0; h < HH; h++) {
      bd[jj][h] += __shfl_xor(bd[jj][h], 1);
      bd[jj][h] += __shfl_xor(bd[jj][h], 2);
    }
  if (csub == 0) {
#pragma unroll
    for (int jj = 0; jj < 4; jj++)
#pragma unroll
      for (int h = 0; h < HH; h++)
        bias_s[h * 256 + jl + jj * 64] = bd[jj][h];
  }
  __syncthreads();
  for (int e = tid; e < HH * 256; e += 256) {
    int h = e >> 8, j2 = e & 255;
    B[((size_t)i * HH + h) * NN + jb + j2] = __float2bfloat16(bias_s[e]);
  }
}

// ---------------------------------------------------------------------------
// ipa_attn: one WARP per (i, h). grid (NN/4, HH), block 256 (4 warps).
// ---------------------------------------------------------------------------
__global__ __launch_bounds__(256) void ipa_attn(
    const float* __restrict__ kc, const float* __restrict__ kpc,
    const float* __restrict__ knc, const float* __restrict__ vc,
    const float* __restrict__ vpc, const float* __restrict__ proj,
    const float* __restrict__ q_pts, const float* __restrict__ qn,
    const float* __restrict__ bb, const float* __restrict__ hw,
    const float* __restrict__ mask,
    __hip_bfloat16* __restrict__ A, float* __restrict__ cat,
    float* __restrict__ optb)
{
  const int h = blockIdx.y;
  const int i = blockIdx.x * 4 + (threadIdx.x >> 6);
  const int lane = threadIdx.x & 63;

  const float* qb = proj + (size_t)i * PROJW + h * 16;
  const float4 q0 = *reinterpret_cast<const float4*>(qb);
  const float4 q1 = *reinterpret_cast<const float4*>(qb + 4);
  const float4 q2 = *reinterpret_cast<const float4*>(qb + 8);
  const float4 q3 = *reinterpret_cast<const float4*>(qb + 12);
  const float* pb = q_pts + (size_t)i * QPR + h * 12;
  const float4 p0 = *reinterpret_cast<const float4*>(pb);
  const float4 p1 = *reinterpret_cast<const float4*>(pb + 4);
  const float4 p2 = *reinterpret_cast<const float4*>(pb + 8);
  const float qnv = qn[i * HH + h];
  const float bbv = bb[h];
  const float hwv = hw[h];
  const float mi = mask[i];

  const float* kch  = kc  + (size_t)h * 16 * NN;
  const float* kpch = kpc + (size_t)h * 12 * NN;
  const float* knch = knc + (size_t)h * NN;
  const float* vch  = vc  + (size_t)h * 16 * NN;
  const float* vpch = vpc + (size_t)h * 24 * NN;
  __hip_bfloat16* Arow = A + ((size_t)i * HH + h) * NN;

  float4 av[4];
#pragma unroll
  for (int t = 0; t < 4; t++) {
    const int j = t * 256 + lane * 4;
    float4 d = {0, 0, 0, 0};
#pragma unroll
    for (int c = 0; c < 16; c++) {
      const float qc = (c < 4 ? (&q0.x)[c] : c < 8 ? (&q1.x)[c - 4]
                       : c < 12 ? (&q2.x)[c - 8] : (&q3.x)[c - 12]);
      float4 kv = *reinterpret_cast<const float4*>(&kch[(size_t)c * NN + j]);
      d.x += qc * kv.x; d.y += qc * kv.y; d.z += qc * kv.z; d.w += qc * kv.w;
    }
    float4 cr = {0, 0, 0, 0};
#pragma unroll
    for (int dd = 0; dd < 12; dd++) {
      const float pc = (dd < 4 ? (&p0.x)[dd] : dd < 8 ? (&p1.x)[dd - 4]
                        : (&p2.x)[dd - 8]);
      float4 kv = *reinterpret_cast<const float4*>(&kpch[(size_t)dd * NN + j]);
      cr.x += pc * kv.x; cr.y += pc * kv.y; cr.z += pc * kv.z; cr.w += pc * kv.w;
    }
    float4 kn4 = *reinterpret_cast<const float4*>(&knch[j]);
    ushort4 bu = *reinterpret_cast<const ushort4*>(&Arow[j]);
    float4 m4 = *reinterpret_cast<const float4*>(&mask[j]);
    av[t].x = SC_QK * d.x + SC_B * (bf2f(bu.x) + bbv)
              - 0.5f * hwv * (qnv + kn4.x - 2.f * cr.x) + INF_ * (mi * m4.x - 1.f);
    av[t].y = SC_QK * d.y + SC_B * (bf2f(bu.y) + bbv)
              - 0.5f * hwv * (qnv + kn4.y - 2.f * cr.y) + INF_ * (mi * m4.y - 1.f);
    av[t].z = SC_QK * d.z + SC_B * (bf2f(bu.z) + bbv)
              - 0.5f * hwv * (qnv + kn4.z - 2.f * cr.z) + INF_ * (mi * m4.z - 1.f);
    av[t].w = SC_QK * d.w + SC_B * (bf2f(bu.w) + bbv)
              - 0.5f * hwv * (qnv + kn4.w - 2.f * cr.w) + INF_ * (mi * m4.w - 1.f);
  }

  float m = av[0].x;
#pragma unroll
  for (int t = 0; t < 4; t++) {
    m = fmaxf(m, av[t].x); m = fmaxf(m, av[t].y);
    m = fmaxf(m, av[t].z); m = fmaxf(m, av[t].w);
  }
  for (int off = 32; off; off >>= 1) m = fmaxf(m, __shfl_xor(m, off));
  float ssum = 0.f;
#pragma unroll
  for (int t = 0; t < 4; t++) {
    av[t].x = __expf(av[t].x - m); ssum += av[t].x;
    av[t].y = __expf(av[t].y - m); ssum += av[t].y;
    av[t].z = __expf(av[t].z - m); ssum += av[t].z;
    av[t].w = __expf(av[t].w - m); ssum += av[t].w;
  }
  for (int off = 32; off; off >>= 1) ssum += __shfl_xor(ssum, off);
  const float inv = 1.f / ssum;
#pragma unroll
  for (int t = 0; t < 4; t++) {
    const int j = t * 256 + lane * 4;
    av[t].x *= inv; av[t].y *= inv; av[t].z *= inv; av[t].w *= inv;
    ushort4 st;
    st.x = f2bf(av[t].x); st.y = f2bf(av[t].y);
    st.z = f2bf(av[t].z); st.w = f2bf(av[t].w);
    *reinterpret_cast<ushort4*>(&Arow[j]) = st;
  }

  float oacc[16], wacc[24];
#pragma unroll
  for (int c = 0; c < 16; c++) oacc[c] = 0.f;
#pragma unroll
  for (int d = 0; d < 24; d++) wacc[d] = 0.f;
#pragma unroll
  for (int t = 0; t < 4; t++) {
    const int j = t * 256 + lane * 4;
    const float4 a4 = av[t];
#pragma unroll
    for (int c = 0; c < 16; c++) {
      float4 vv = *reinterpret_cast<const float4*>(&vch[(size_t)c * NN + j]);
      oacc[c] += dot4(a4, vv);
    }
#pragma unroll
    for (int d = 0; d < 24; d++) {
      float4 wv = *reinterpret_cast<const float4*>(&vpch[(size_t)d * NN + j]);
      wacc[d] += dot4(a4, wv);
    }
  }
  for (int off = 32; off; off >>= 1) {
#pragma unroll
    for (int c = 0; c < 16; c++) oacc[c] += __shfl_xor(oacc[c], off);
#pragma unroll
    for (int d = 0; d < 24; d++) wacc[d] += __shfl_xor(wacc[d], off);
  }
  if (lane == 0) {
    float* cr = cat + (size_t)i * DCAT + h * 16;
#pragma unroll
    for (int c = 0; c < 16; c++) cr[c] = oacc[c];
    float* ob = optb + ((size_t)i * HH + h) * 24;
#pragma unroll
    for (int d = 0; d < 24; d++) ob[d] = wacc[d];
  }
}

// ---------------------------------------------------------------------------
// ipa_finish: inverse-rotate o_pt, norms -> cat[192:576]. grid NN, block 128.
// ---------------------------------------------------------------------------
__global__ __launch_bounds__(128) void ipa_finish(
    const float* __restrict__ optb, const float* __restrict__ rot,
    const float* __restrict__ trans, float* __restrict__ cat)
{
  const int i = blockIdx.x, tid = threadIdx.x;
  __shared__ float R_s[9], T_s[3];
  if (tid < 9) R_s[tid] = rot[i * 9 + tid];
  if (tid < 3) T_s[tid] = trans[i * 3 + tid];
  __syncthreads();
  if (tid < 96) {
    int h = tid >> 3, p = tid & 7;
    const float* ob = optb + ((size_t)i * HH + h) * 24 + p * 3;
    float gx = ob[0] - T_s[0];
    float gy = ob[1] - T_s[1];
    float gz = ob[2] - T_s[2];
    float lx = R_s[0] * gx + R_s[3] * gy + R_s[6] * gz;
    float ly = R_s[1] * gx + R_s[4] * gy + R_s[7] * gz;
    float lz = R_s[2] * gx + R_s[5] * gy + R_s[8] * gz;
    float* catr = cat + (size_t)i * DCAT;
    catr[192 + 0 * 96 + h * 8 + p] = lx;
    catr[192 + 1 * 96 + h * 8 + p] = ly;
    catr[192 + 2 * 96 + h * 8 + p] = lz;
    catr[480 + h * 8 + p] = sqrtf(lx * lx + ly * ly + lz * lz + 1e-8f);
  }
}

// ---------------------------------------------------------------------------
// opair_pass v2: o_pair[i,h,c] = sum_j A[i,h,j]*z[i,j,c]. One block per i.
// A staged once transposed (A_ls[j][h], fp32, 48 KB); z read DIRECTLY from
// global (coalesced over c) — no barriers in the j loop.
// Thread = (c4 = (tid&31)*4, jsub = tid>>5 owning 128 contiguous j).
// ---------------------------------------------------------------------------
__global__ __launch_bounds__(256) void opair_pass(
    const float* __restrict__ z, const __hip_bfloat16* __restrict__ A,
    float* __restrict__ cat)
{
  __shared__ float A_ls[NN * HH];   // [j][h], 48 KB
  __shared__ float red[HH * CZ];    // 6 KB
  const int i = blockIdx.x, tid = threadIdx.x;
  const int c4 = (tid & 31) * 4, jsub = tid >> 5;

  for (int e = tid; e < HH * NN; e += 256) {
    int h = e >> 10, j = e & 1023;
    A_ls[j * HH + h] = __bfloat162float(A[(size_t)(i * HH + h) * NN + j]);
  }
  for (int e = tid; e < HH * CZ; e += 256) red[e] = 0.f;
  __syncthreads();

  float4 acc[HH];
#pragma unroll
  for (int h = 0; h < HH; h++) acc[h] = make_float4(0.f, 0.f, 0.f, 0.f);

  const float* zrow = z + ((size_t)i * NN + jsub * 128) * CZ + c4;
  const float* arow = &A_ls[jsub * 128 * HH];
  for (int j0 = 0; j0 < 128; j0 += 4) {
#pragma unroll
    for (int jj = 0; jj < 4; jj++) {
      const int j = j0 + jj;
      float4 zq = *reinterpret_cast<const float4*>(&zrow[(size_t)j * CZ]);
      float4 a0 = *reinterpret_cast<const float4*>(&arow[j * HH]);
      float4 a1 = *reinterpret_cast<const float4*>(&arow[j * HH + 4]);
      float4 a2 = *reinterpret_cast<const float4*>(&arow[j * HH + 8]);
      acc[0].x += a0.x * zq.x; acc[0].y += a0.x * zq.y;
      acc[0].z += a0.x * zq.z; acc[0].w += a0.x * zq.w;
      acc[1].x += a0.y * zq.x; acc[1].y += a0.y * zq.y;
      acc[1].z += a0.y * zq.z; acc[1].w += a0.y * zq.w;
      acc[2].x += a0.z * zq.x; acc[2].y += a0.z * zq.y;
      acc[2].z += a0.z * zq.z; acc[2].w += a0.z * zq.w;
      acc[3].x += a0.w * zq.x; acc[3].y += a0.w * zq.y;
      acc[3].z += a0.w * zq.z; acc[3].w += a0.w * zq.w;
      acc[4].x += a1.x * zq.x; acc[4].y += a1.x * zq.y;
      acc[4].z += a1.x * zq.z; acc[4].w += a1.x * zq.w;
      acc[5].x += a1.y * zq.x; acc[5].y += a1.y * zq.y;
      acc[5].z += a1.y * zq.z; acc[5].w += a1.y * zq.w;
      acc[6].x += a1.z * zq.x; acc[6].y += a1.z * zq.y;
      acc[6].z += a1.z * zq.z; acc[6].w += a1.z * zq.w;
      acc[7].x += a1.w * zq.x; acc[7].y += a1.w * zq.y;
      acc[7].z += a1.w * zq.z; acc[7].w += a1.w * zq.w;
      acc[8].x += a2.x * zq.x; acc[8].y += a2.x * zq.y;
      acc[8].z += a2.x * zq.z; acc[8].w += a2.x * zq.w;
      acc[9].x += a2.y * zq.x; acc[9].y += a2.y * zq.y;
      acc[9].z += a2.y * zq.z; acc[9].w += a2.y * zq.w;
      acc[10].x += a2.z * zq.x; acc[10].y += a2.z * zq.y;
      acc[10].z += a2.z * zq.z; acc[10].w += a2.z * zq.w;
      acc[11].x += a2.w * zq.x; acc[11].y += a2.w * zq.y;
      acc[11].z += a2.w * zq.z; acc[11].w += a2.w * zq.w;
    }
  }
  // cross-jsub reduction (8 barrier-separated steps)
  for (int s = 0; s < 8; s++) {
    __syncthreads();
    if (jsub == s) {
#pragma unroll
      for (int h = 0; h < HH; h++) {
        red[h * CZ + c4 + 0] += acc[h].x;
        red[h * CZ + c4 + 1] += acc[h].y;
        red[h * CZ + c4 + 2] += acc[h].z;
        red[h * CZ + c4 + 3] += acc[h].w;
      }
    }
  }
  __syncthreads();
  for (int e = tid; e < HH * CZ; e += 256)
    cat[(size_t)i * DCAT + 576 + e] = red[e];
}

// ---------------------------------------------------------------------------
// out_gemm: out = cat @ wout + bout  (1024 x 2112 x 384)
// ---------------------------------------------------------------------------
__global__ __launch_bounds__(256) void out_gemm(
    const float* __restrict__ cat, const float* __restrict__ wout,
    const float* __restrict__ bout, float* __restrict__ out)
{
  __shared__ float c_lds[4 * DCAT];
  const int n0 = blockIdx.x * 4;
  const int cq = blockIdx.y * 128 + (threadIdx.x & 63) * 2;
  const int rg = threadIdx.x >> 6;
  for (int idx = threadIdx.x; idx < 4 * DCAT; idx += 256) {
    int r = idx / DCAT, kk = idx - r * DCAT;
    c_lds[idx] = cat[(size_t)(n0 + r) * DCAT + kk];
  }
  __syncthreads();
  float a0 = 0.f, a1 = 0.f;
  const float* crow = &c_lds[rg * DCAT];
#pragma unroll 4
  for (int kk = 0; kk < DCAT; kk++) {
    float cv = crow[kk];
    float2 w2 = *reinterpret_cast<const float2*>(&wout[(size_t)kk * CS + cq]);
    a0 += cv * w2.x; a1 += cv * w2.y;
  }
  float* o = out + (size_t)(n0 + rg) * CS + cq;
  o[0] = a0 + bout[cq]; o[1] = a1 + bout[cq + 1];
}

// ---------------------------------------------------------------------------
extern "C" void kernel_launch(void* const* d_in, const int* in_sizes, int n_in,
                              void* d_out, int out_size, void* d_ws, size_t ws_size,
                              hipStream_t stream) {
  const float* s      = (const float*)d_in[0];
  const float* z      = (const float*)d_in[1];
  const float* rot    = (const float*)d_in[2];
  const float* trans  = (const float*)d_in[3];
  const float* mask   = (const float*)d_in[4];
  const float* wq     = (const float*)d_in[5];
  const float* bq     = (const float*)d_in[6];
  const float* wkv    = (const float*)d_in[7];
  const float* bkv    = (const float*)d_in[8];
  const float* wqp    = (const float*)d_in[9];
  const float* bqp    = (const float*)d_in[10];
  const float* wkvp   = (const float*)d_in[11];
  const float* bkvp   = (const float*)d_in[12];
  const float* wb     = (const float*)d_in[13];
  const float* bb     = (const float*)d_in[14];
  const float* head_w = (const float*)d_in[15];
  const float* wout   = (const float*)d_in[16];
  const float* bout   = (const float*)d_in[17];
  float* out = (float*)d_out;

  // workspace layout (floats; all bases 16-float aligned)
  float* ws = (float*)d_ws;
  float* proj_buf = ws;                                  // 1,179,648
  float* kc_buf   = proj_buf + (size_t)NN * PROJW;       // 196,608
  float* vc_buf   = kc_buf + (size_t)HH * 16 * NN;       // 196,608
  float* kpc_buf  = vc_buf + (size_t)HH * 16 * NN;       // 147,456
  float* vpc_buf  = kpc_buf + (size_t)HH * 12 * NN;      // 294,912
  float* knc_buf  = vpc_buf + (size_t)HH * 24 * NN;      // 12,288
  float* qpts_buf = knc_buf + (size_t)HH * NN;           // 147,456
  float* qn_buf   = qpts_buf + (size_t)NN * QPR;         // 12,288
  float* wbt_buf  = qn_buf + NN * HH;                    // 1,536
  float* hw_buf   = wbt_buf + HH * CZ;                   // 16
  float* optb_buf = hw_buf + 16;                         // 294,912
  float* cat_buf  = optb_buf + (size_t)NN * HH * 24;     // 2,162,688
  __hip_bfloat16* A_buf =
      (__hip_bfloat16*)(cat_buf + (size_t)NN * DCAT);    // 12,582,912 bf16

  prep<<<dim3(1), dim3(256), 0, stream>>>(wb, head_w, wbt_buf, hw_buf);
  proj_all<<<dim3(NN / 8, 9), dim3(256), 0, stream>>>(
      s, wq, bq, wkv, bkv, wqp, bqp, wkvp, bkvp, proj_buf);
  ipa_transform<<<dim3(NN), dim3(256), 0, stream>>>(
      proj_buf, rot, trans, kc_buf, vc_buf, qpts_buf, kpc_buf, vpc_buf,
      qn_buf, knc_buf);
  bias_pass<<<dim3(4, NN), dim3(256), 0, stream>>>(z, wbt_buf, A_buf);
  ipa_attn<<<dim3(NN / 4, HH), dim3(256), 0, stream>>>(
      kc_buf, kpc_buf, knc_buf, vc_buf, vpc_buf, proj_buf, qpts_buf,
      qn_buf, bb, hw_buf, mask, A_buf, cat_buf, optb_buf);
  ipa_finish<<<dim3(NN), dim3(128), 0, stream>>>(optb_buf, rot, trans, cat_buf);
  opair_pass<<<dim3(NN), dim3(256), 0, stream>>>(z, A_buf, cat_buf);
  out_gemm<<<dim3(NN / 4, 3), dim3(256), 0, stream>>>(
      cat_buf, wout, bout, out);
}

// Round 6
// 738.449 us; speedup vs baseline: 5.3109x; 1.0235x over previous
//
#include <hip/hip_runtime.h>
#include <hip/hip_bf16.h>
#include <math.h>

// Problem constants
#define NN   1024
#define CS   384
#define CZ   128
#define HH   12
#define HCH  192
#define QPR  144
#define DCAT 2112
#define PROJW 1152    // 192+384+144+432
#define INF_ 100000.0f

#define SC_QK 0.14433756729740643f   // sqrt(1/48)
#define SC_B  0.5773502691896258f    // sqrt(1/3)
#define SC_PT 0.13608276348795434f   // sqrt(1/54)

__device__ __forceinline__ float dot4(float4 a, float4 b) {
  return a.x * b.x + a.y * b.y + a.z * b.z + a.w * b.w;
}
__device__ __forceinline__ float bf2f(unsigned short u) {
  unsigned int v = ((unsigned int)u) << 16;
  float f; __builtin_memcpy(&f, &v, 4); return f;
}
__device__ __forceinline__ unsigned short f2bf(float f) {
  __hip_bfloat16 h = __float2bfloat16(f);
  unsigned short u; __builtin_memcpy(&u, &h, 2); return u;
}

// ---------------------------------------------------------------------------
// prep: wb_t[h][c] transpose + softplus(head_w) scale
// ---------------------------------------------------------------------------
__global__ void prep(const float* __restrict__ wb, const float* __restrict__ head_w,
                     float* __restrict__ wb_t, float* __restrict__ hw)
{
  int t = threadIdx.x;
  for (int idx = t; idx < CZ * HH; idx += 256) {
    int c = idx % CZ, h = idx / CZ;
    wb_t[h * CZ + c] = wb[c * HH + h];
  }
  if (t < HH) {
    float x = head_w[t];
    float sp = (x > 20.f) ? x : log1pf(__expf(x));
    hw[t] = sp * SC_PT;
  }
}

// ---------------------------------------------------------------------------
// proj_all: fused s @ {wq,wkv,wqp,wkvp} + bias -> proj[n][1152]
// ---------------------------------------------------------------------------
__global__ __launch_bounds__(256) void proj_all(
    const float* __restrict__ s,
    const float* __restrict__ wq, const float* __restrict__ bq,
    const float* __restrict__ wkv, const float* __restrict__ bkv,
    const float* __restrict__ wqp, const float* __restrict__ bqp,
    const float* __restrict__ wkvp, const float* __restrict__ bkvp,
    float* __restrict__ proj)
{
  __shared__ float s_lds[8 * CS];
  const int n0 = blockIdx.x * 8;
  for (int idx = threadIdx.x; idx < 8 * CS; idx += 256)
    s_lds[idx] = s[(size_t)(n0 + idx / CS) * CS + (idx % CS)];
  __syncthreads();

  const int gc = blockIdx.y * 128 + (threadIdx.x & 31) * 4;
  const int rg = threadIdx.x >> 5;
  const float* wp; const float* bp; int OUT, lc;
  if (gc < 192)      { wp = wq;   bp = bq;   OUT = 192; lc = gc; }
  else if (gc < 576) { wp = wkv;  bp = bkv;  OUT = 384; lc = gc - 192; }
  else if (gc < 720) { wp = wqp;  bp = bqp;  OUT = 144; lc = gc - 576; }
  else               { wp = wkvp; bp = bkvp; OUT = 432; lc = gc - 720; }

  float a0 = 0.f, a1 = 0.f, a2 = 0.f, a3 = 0.f;
  const float* srow = &s_lds[rg * CS];
#pragma unroll 4
  for (int kk = 0; kk < CS; kk++) {
    float sv = srow[kk];
    float4 w4 = *reinterpret_cast<const float4*>(&wp[(size_t)kk * OUT + lc]);
    a0 += sv * w4.x; a1 += sv * w4.y; a2 += sv * w4.z; a3 += sv * w4.w;
  }
  float* o = proj + (size_t)(n0 + rg) * PROJW + gc;
  o[0] = a0 + bp[lc]; o[1] = a1 + bp[lc + 1];
  o[2] = a2 + bp[lc + 2]; o[3] = a3 + bp[lc + 3];
}

// ---------------------------------------------------------------------------
// transform: split kv, rotate/translate points, write COMPONENT-MAJOR layouts
// ---------------------------------------------------------------------------
__global__ __launch_bounds__(256) void ipa_transform(
    const float* __restrict__ proj, const float* __restrict__ rot,
    const float* __restrict__ trans,
    float* __restrict__ kc, float* __restrict__ vc,
    float* __restrict__ q_pts, float* __restrict__ kpc,
    float* __restrict__ vpc, float* __restrict__ qn, float* __restrict__ knc)
{
  const int n = blockIdx.x, tid = threadIdx.x;
  const float* pr = proj + (size_t)n * PROJW;
  __shared__ float R[9], T[3], sq_q[48], sq_k[48];
  if (tid < 9) R[tid] = rot[n * 9 + tid];
  if (tid < 3) T[tid] = trans[n * 3 + tid];
  __syncthreads();
  if (tid < HCH) {
    int h = tid >> 4, c = tid & 15;
    kc[(size_t)(h * 16 + c) * NN + n] = pr[192 + h * 32 + c];
    vc[(size_t)(h * 16 + c) * NN + n] = pr[192 + h * 32 + 16 + c];
  }
  if (tid < 48) {
    float r0 = pr[576 + tid], r1 = pr[576 + 48 + tid], r2 = pr[576 + 96 + tid];
    float x = R[0] * r0 + R[1] * r1 + R[2] * r2 + T[0];
    float y = R[3] * r0 + R[4] * r1 + R[5] * r2 + T[1];
    float z = R[6] * r0 + R[7] * r1 + R[8] * r2 + T[2];
    q_pts[(size_t)n * QPR + tid * 3 + 0] = x;
    q_pts[(size_t)n * QPR + tid * 3 + 1] = y;
    q_pts[(size_t)n * QPR + tid * 3 + 2] = z;
    sq_q[tid] = x * x + y * y + z * z;
  }
  if (tid >= 64 && tid < 208) {
    int t = tid - 64;
    float r0 = pr[720 + t], r1 = pr[720 + 144 + t], r2 = pr[720 + 288 + t];
    float x = R[0] * r0 + R[1] * r1 + R[2] * r2 + T[0];
    float y = R[3] * r0 + R[4] * r1 + R[5] * r2 + T[1];
    float z = R[6] * r0 + R[7] * r1 + R[8] * r2 + T[2];
    int h = t / 12, pp = t % 12;
    if (pp < 4) {
      int d = pp * 3;
      kpc[(size_t)(h * 12 + d + 0) * NN + n] = x;
      kpc[(size_t)(h * 12 + d + 1) * NN + n] = y;
      kpc[(size_t)(h * 12 + d + 2) * NN + n] = z;
      sq_k[h * 4 + pp] = x * x + y * y + z * z;
    } else {
      int d = (pp - 4) * 3;
      vpc[(size_t)(h * 24 + d + 0) * NN + n] = x;
      vpc[(size_t)(h * 24 + d + 1) * NN + n] = y;
      vpc[(size_t)(h * 24 + d + 2) * NN + n] = z;
    }
  }
  __syncthreads();
  if (tid < HH) {
    float a = 0.f, b = 0.f;
#pragma unroll
    for (int p = 0; p < 4; p++) { a += sq_q[tid * 4 + p]; b += sq_k[tid * 4 + p]; }
    qn[n * HH + tid] = a;
    knc[(size_t)tid * NN + n] = b;
  }
}

// ---------------------------------------------------------------------------
// bias_pass v3: B[i,h,j] = sum_c z[i,j,c]*wb_t[h,c] (bf16 out).
// grid (8, 1024), block 256. Thread (jl=tid>>2, csub=tid&3) handles 2 rows
// (j = jb+jl, jb+64+jl); z read directly from global; rolling wb fragment
// (low VGPR -> ~8 waves/SIMD for TLP latency hiding).
// ---------------------------------------------------------------------------
__global__ __launch_bounds__(256) void bias_pass(
    const float* __restrict__ z, const float* __restrict__ wb_t,
    __hip_bfloat16* __restrict__ B)
{
  __shared__ float wb_s[HH * CZ];      // 6 KB
  __shared__ float bias_s[HH * 128];   // 6 KB
  const int i = blockIdx.y;
  const int jb = blockIdx.x * 128;
  const int tid = threadIdx.x;
  const int jl = tid >> 2, csub = tid & 3;

  for (int e = tid; e < HH * CZ; e += 256) wb_s[e] = wb_t[e];
  __syncthreads();

  float bd0[HH], bd1[HH];
#pragma unroll
  for (int h = 0; h < HH; h++) { bd0[h] = 0.f; bd1[h] = 0.f; }

  const float* zb = z + ((size_t)i * NN + jb + jl) * CZ + csub * 4;
#pragma unroll
  for (int k8 = 0; k8 < 8; k8++) {
    float4 zq0 = *reinterpret_cast<const float4*>(&zb[k8 * 16]);
    float4 zq1 = *reinterpret_cast<const float4*>(&zb[(size_t)64 * CZ + k8 * 16]);
    const int c = csub * 4 + k8 * 16;
#pragma unroll
    for (int h = 0; h < HH; h++) {
      float4 wv = *reinterpret_cast<const float4*>(&wb_s[h * CZ + c]);
      bd0[h] += dot4(zq0, wv);
      bd1[h] += dot4(zq1, wv);
    }
  }
#pragma unroll
  for (int h = 0; h < HH; h++) {
    bd0[h] += __shfl_xor(bd0[h], 1); bd0[h] += __shfl_xor(bd0[h], 2);
    bd1[h] += __shfl_xor(bd1[h], 1); bd1[h] += __shfl_xor(bd1[h], 2);
  }
  if (csub == 0) {
#pragma unroll
    for (int h = 0; h < HH; h++) {
      bias_s[h * 128 + jl] = bd0[h];
      bias_s[h * 128 + 64 + jl] = bd1[h];
    }
  }
  __syncthreads();
  for (int e = tid; e < HH * 128; e += 256) {
    int h = e >> 7, j2 = e & 127;
    B[((size_t)i * HH + h) * NN + jb + j2] = __float2bfloat16(bias_s[e]);
  }
}

// ---------------------------------------------------------------------------
// ipa_attn: one WARP per (i, h). grid (NN/4, HH), block 256 (4 warps).
// ---------------------------------------------------------------------------
__global__ __launch_bounds__(256) void ipa_attn(
    const float* __restrict__ kc, const float* __restrict__ kpc,
    const float* __restrict__ knc, const float* __restrict__ vc,
    const float* __restrict__ vpc, const float* __restrict__ proj,
    const float* __restrict__ q_pts, const float* __restrict__ qn,
    const float* __restrict__ bb, const float* __restrict__ hw,
    const float* __restrict__ mask,
    __hip_bfloat16* __restrict__ A, float* __restrict__ cat,
    float* __restrict__ optb)
{
  const int h = blockIdx.y;
  const int i = blockIdx.x * 4 + (threadIdx.x >> 6);
  const int lane = threadIdx.x & 63;

  const float* qb = proj + (size_t)i * PROJW + h * 16;
  const float4 q0 = *reinterpret_cast<const float4*>(qb);
  const float4 q1 = *reinterpret_cast<const float4*>(qb + 4);
  const float4 q2 = *reinterpret_cast<const float4*>(qb + 8);
  const float4 q3 = *reinterpret_cast<const float4*>(qb + 12);
  const float* pb = q_pts + (size_t)i * QPR + h * 12;
  const float4 p0 = *reinterpret_cast<const float4*>(pb);
  const float4 p1 = *reinterpret_cast<const float4*>(pb + 4);
  const float4 p2 = *reinterpret_cast<const float4*>(pb + 8);
  const float qnv = qn[i * HH + h];
  const float bbv = bb[h];
  const float hwv = hw[h];
  const float mi = mask[i];

  const float* kch  = kc  + (size_t)h * 16 * NN;
  const float* kpch = kpc + (size_t)h * 12 * NN;
  const float* knch = knc + (size_t)h * NN;
  const float* vch  = vc  + (size_t)h * 16 * NN;
  const float* vpch = vpc + (size_t)h * 24 * NN;
  __hip_bfloat16* Arow = A + ((size_t)i * HH + h) * NN;

  float4 av[4];
#pragma unroll
  for (int t = 0; t < 4; t++) {
    const int j = t * 256 + lane * 4;
    float4 d = {0, 0, 0, 0};
#pragma unroll
    for (int c = 0; c < 16; c++) {
      const float qc = (c < 4 ? (&q0.x)[c] : c < 8 ? (&q1.x)[c - 4]
                       : c < 12 ? (&q2.x)[c - 8] : (&q3.x)[c - 12]);
      float4 kv = *reinterpret_cast<const float4*>(&kch[(size_t)c * NN + j]);
      d.x += qc * kv.x; d.y += qc * kv.y; d.z += qc * kv.z; d.w += qc * kv.w;
    }
    float4 cr = {0, 0, 0, 0};
#pragma unroll
    for (int dd = 0; dd < 12; dd++) {
      const float pc = (dd < 4 ? (&p0.x)[dd] : dd < 8 ? (&p1.x)[dd - 4]
                        : (&p2.x)[dd - 8]);
      float4 kv = *reinterpret_cast<const float4*>(&kpch[(size_t)dd * NN + j]);
      cr.x += pc * kv.x; cr.y += pc * kv.y; cr.z += pc * kv.z; cr.w += pc * kv.w;
    }
    float4 kn4 = *reinterpret_cast<const float4*>(&knch[j]);
    ushort4 bu = *reinterpret_cast<const ushort4*>(&Arow[j]);
    float4 m4 = *reinterpret_cast<const float4*>(&mask[j]);
    av[t].x = SC_QK * d.x + SC_B * (bf2f(bu.x) + bbv)
              - 0.5f * hwv * (qnv + kn4.x - 2.f * cr.x) + INF_ * (mi * m4.x - 1.f);
    av[t].y = SC_QK * d.y + SC_B * (bf2f(bu.y) + bbv)
              - 0.5f * hwv * (qnv + kn4.y - 2.f * cr.y) + INF_ * (mi * m4.y - 1.f);
    av[t].z = SC_QK * d.z + SC_B * (bf2f(bu.z) + bbv)
              - 0.5f * hwv * (qnv + kn4.z - 2.f * cr.z) + INF_ * (mi * m4.z - 1.f);
    av[t].w = SC_QK * d.w + SC_B * (bf2f(bu.w) + bbv)
              - 0.5f * hwv * (qnv + kn4.w - 2.f * cr.w) + INF_ * (mi * m4.w - 1.f);
  }

  float m = av[0].x;
#pragma unroll
  for (int t = 0; t < 4; t++) {
    m = fmaxf(m, av[t].x); m = fmaxf(m, av[t].y);
    m = fmaxf(m, av[t].z); m = fmaxf(m, av[t].w);
  }
  for (int off = 32; off; off >>= 1) m = fmaxf(m, __shfl_xor(m, off));
  float ssum = 0.f;
#pragma unroll
  for (int t = 0; t < 4; t++) {
    av[t].x = __expf(av[t].x - m); ssum += av[t].x;
    av[t].y = __expf(av[t].y - m); ssum += av[t].y;
    av[t].z = __expf(av[t].z - m); ssum += av[t].z;
    av[t].w = __expf(av[t].w - m); ssum += av[t].w;
  }
  for (int off = 32; off; off >>= 1) ssum += __shfl_xor(ssum, off);
  const float inv = 1.f / ssum;
#pragma unroll
  for (int t = 0; t < 4; t++) {
    const int j = t * 256 + lane * 4;
    av[t].x *= inv; av[t].y *= inv; av[t].z *= inv; av[t].w *= inv;
    ushort4 st;
    st.x = f2bf(av[t].x); st.y = f2bf(av[t].y);
    st.z = f2bf(av[t].z); st.w = f2bf(av[t].w);
    *reinterpret_cast<ushort4*>(&Arow[j]) = st;
  }

  float oacc[16], wacc[24];
#pragma unroll
  for (int c = 0; c < 16; c++) oacc[c] = 0.f;
#pragma unroll
  for (int d = 0; d < 24; d++) wacc[d] = 0.f;
#pragma unroll
  for (int t = 0; t < 4; t++) {
    const int j = t * 256 + lane * 4;
    const float4 a4 = av[t];
#pragma unroll
    for (int c = 0; c < 16; c++) {
      float4 vv = *reinterpret_cast<const float4*>(&vch[(size_t)c * NN + j]);
      oacc[c] += dot4(a4, vv);
    }
#pragma unroll
    for (int d = 0; d < 24; d++) {
      float4 wv = *reinterpret_cast<const float4*>(&vpch[(size_t)d * NN + j]);
      wacc[d] += dot4(a4, wv);
    }
  }
  for (int off = 32; off; off >>= 1) {
#pragma unroll
    for (int c = 0; c < 16; c++) oacc[c] += __shfl_xor(oacc[c], off);
#pragma unroll
    for (int d = 0; d < 24; d++) wacc[d] += __shfl_xor(wacc[d], off);
  }
  if (lane == 0) {
    float* cr = cat + (size_t)i * DCAT + h * 16;
#pragma unroll
    for (int c = 0; c < 16; c++) cr[c] = oacc[c];
    float* ob = optb + ((size_t)i * HH + h) * 24;
#pragma unroll
    for (int d = 0; d < 24; d++) ob[d] = wacc[d];
  }
}

// ---------------------------------------------------------------------------
// ipa_finish: inverse-rotate o_pt, norms -> cat[192:576]. grid NN, block 128.
// ---------------------------------------------------------------------------
__global__ __launch_bounds__(128) void ipa_finish(
    const float* __restrict__ optb, const float* __restrict__ rot,
    const float* __restrict__ trans, float* __restrict__ cat)
{
  const int i = blockIdx.x, tid = threadIdx.x;
  __shared__ float R_s[9], T_s[3];
  if (tid < 9) R_s[tid] = rot[i * 9 + tid];
  if (tid < 3) T_s[tid] = trans[i * 3 + tid];
  __syncthreads();
  if (tid < 96) {
    int h = tid >> 3, p = tid & 7;
    const float* ob = optb + ((size_t)i * HH + h) * 24 + p * 3;
    float gx = ob[0] - T_s[0];
    float gy = ob[1] - T_s[1];
    float gz = ob[2] - T_s[2];
    float lx = R_s[0] * gx + R_s[3] * gy + R_s[6] * gz;
    float ly = R_s[1] * gx + R_s[4] * gy + R_s[7] * gz;
    float lz = R_s[2] * gx + R_s[5] * gy + R_s[8] * gz;
    float* catr = cat + (size_t)i * DCAT;
    catr[192 + 0 * 96 + h * 8 + p] = lx;
    catr[192 + 1 * 96 + h * 8 + p] = ly;
    catr[192 + 2 * 96 + h * 8 + p] = lz;
    catr[480 + h * 8 + p] = sqrtf(lx * lx + ly * ly + lz * lz + 1e-8f);
  }
}

// ---------------------------------------------------------------------------
// opair_pass v3: o_pair[i,h,c] = sum_j A[i,h,j]*z[i,j,c]. One block per i.
// A staged in TWO 512-row halves (A_ls[j][h] fp32, 24 KB) -> 30 KB LDS total
// -> 5 blocks/CU. z read directly from global (coalesced); no barriers
// inside the j loop. Thread = (c4=(tid&31)*4, jsub=tid>>5 owns 64 j/half).
// ---------------------------------------------------------------------------
__global__ __launch_bounds__(256) void opair_pass(
    const float* __restrict__ z, const __hip_bfloat16* __restrict__ A,
    float* __restrict__ cat)
{
  __shared__ float A_ls[512 * HH];  // 24 KB
  __shared__ float red[HH * CZ];    // 6 KB
  const int i = blockIdx.x, tid = threadIdx.x;
  const int c4 = (tid & 31) * 4, jsub = tid >> 5;

  for (int e = tid; e < HH * CZ; e += 256) red[e] = 0.f;

  float4 acc[HH];
#pragma unroll
  for (int h = 0; h < HH; h++) acc[h] = make_float4(0.f, 0.f, 0.f, 0.f);

  for (int half = 0; half < 2; half++) {
    __syncthreads();  // protect A_ls from previous-half readers
    // stage A half, vectorized ushort4 (4 j at a time)
    for (int e = tid; e < HH * 128; e += 256) {
      int h = e >> 7, j4 = (e & 127) * 4;
      ushort4 au = *reinterpret_cast<const ushort4*>(
          &A[((size_t)i * HH + h) * NN + half * 512 + j4]);
      A_ls[(j4 + 0) * HH + h] = bf2f(au.x);
      A_ls[(j4 + 1) * HH + h] = bf2f(au.y);
      A_ls[(j4 + 2) * HH + h] = bf2f(au.z);
      A_ls[(j4 + 3) * HH + h] = bf2f(au.w);
    }
    __syncthreads();

    const float* zrow = z + ((size_t)i * NN + half * 512 + jsub * 64) * CZ + c4;
    const float* arow = &A_ls[jsub * 64 * HH];
    for (int j0 = 0; j0 < 64; j0 += 4) {
#pragma unroll
      for (int jj = 0; jj < 4; jj++) {
        const int j = j0 + jj;
        float4 zq = *reinterpret_cast<const float4*>(&zrow[(size_t)j * CZ]);
        float4 a0 = *reinterpret_cast<const float4*>(&arow[j * HH]);
        float4 a1 = *reinterpret_cast<const float4*>(&arow[j * HH + 4]);
        float4 a2 = *reinterpret_cast<const float4*>(&arow[j * HH + 8]);
        acc[0].x += a0.x * zq.x; acc[0].y += a0.x * zq.y;
        acc[0].z += a0.x * zq.z; acc[0].w += a0.x * zq.w;
        acc[1].x += a0.y * zq.x; acc[1].y += a0.y * zq.y;
        acc[1].z += a0.y * zq.z; acc[1].w += a0.y * zq.w;
        acc[2].x += a0.z * zq.x; acc[2].y += a0.z * zq.y;
        acc[2].z += a0.z * zq.z; acc[2].w += a0.z * zq.w;
        acc[3].x += a0.w * zq.x; acc[3].y += a0.w * zq.y;
        acc[3].z += a0.w * zq.z; acc[3].w += a0.w * zq.w;
        acc[4].x += a1.x * zq.x; acc[4].y += a1.x * zq.y;
        acc[4].z += a1.x * zq.z; acc[4].w += a1.x * zq.w;
        acc[5].x += a1.y * zq.x; acc[5].y += a1.y * zq.y;
        acc[5].z += a1.y * zq.z; acc[5].w += a1.y * zq.w;
        acc[6].x += a1.z * zq.x; acc[6].y += a1.z * zq.y;
        acc[6].z += a1.z * zq.z; acc[6].w += a1.z * zq.w;
        acc[7].x += a1.w * zq.x; acc[7].y += a1.w * zq.y;
        acc[7].z += a1.w * zq.z; acc[7].w += a1.w * zq.w;
        acc[8].x += a2.x * zq.x; acc[8].y += a2.x * zq.y;
        acc[8].z += a2.x * zq.z; acc[8].w += a2.x * zq.w;
        acc[9].x += a2.y * zq.x; acc[9].y += a2.y * zq.y;
        acc[9].z += a2.y * zq.z; acc[9].w += a2.y * zq.w;
        acc[10].x += a2.z * zq.x; acc[10].y += a2.z * zq.y;
        acc[10].z += a2.z * zq.z; acc[10].w += a2.z * zq.w;
        acc[11].x += a2.w * zq.x; acc[11].y += a2.w * zq.y;
        acc[11].z += a2.w * zq.z; acc[11].w += a2.w * zq.w;
      }
    }
  }
  // cross-jsub reduction (8 barrier-separated steps)
  for (int s = 0; s < 8; s++) {
    __syncthreads();
    if (jsub == s) {
#pragma unroll
      for (int h = 0; h < HH; h++) {
        red[h * CZ + c4 + 0] += acc[h].x;
        red[h * CZ + c4 + 1] += acc[h].y;
        red[h * CZ + c4 + 2] += acc[h].z;
        red[h * CZ + c4 + 3] += acc[h].w;
      }
    }
  }
  __syncthreads();
  for (int e = tid; e < HH * CZ; e += 256)
    cat[(size_t)i * DCAT + 576 + e] = red[e];
}

// ---------------------------------------------------------------------------
// out_gemm: out = cat @ wout + bout  (1024 x 2112 x 384)
// ---------------------------------------------------------------------------
__global__ __launch_bounds__(256) void out_gemm(
    const float* __restrict__ cat, const float* __restrict__ wout,
    const float* __restrict__ bout, float* __restrict__ out)
{
  __shared__ float c_lds[4 * DCAT];
  const int n0 = blockIdx.x * 4;
  const int cq = blockIdx.y * 128 + (threadIdx.x & 63) * 2;
  const int rg = threadIdx.x >> 6;
  for (int idx = threadIdx.x; idx < 4 * DCAT; idx += 256) {
    int r = idx / DCAT, kk = idx - r * DCAT;
    c_lds[idx] = cat[(size_t)(n0 + r) * DCAT + kk];
  }
  __syncthreads();
  float a0 = 0.f, a1 = 0.f;
  const float* crow = &c_lds[rg * DCAT];
#pragma unroll 4
  for (int kk = 0; kk < DCAT; kk++) {
    float cv = crow[kk];
    float2 w2 = *reinterpret_cast<const float2*>(&wout[(size_t)kk * CS + cq]);
    a0 += cv * w2.x; a1 += cv * w2.y;
  }
  float* o = out + (size_t)(n0 + rg) * CS + cq;
  o[0] = a0 + bout[cq]; o[1] = a1 + bout[cq + 1];
}

// ---------------------------------------------------------------------------
extern "C" void kernel_launch(void* const* d_in, const int* in_sizes, int n_in,
                              void* d_out, int out_size, void* d_ws, size_t ws_size,
                              hipStream_t stream) {
  const float* s      = (const float*)d_in[0];
  const float* z      = (const float*)d_in[1];
  const float* rot    = (const float*)d_in[2];
  const float* trans  = (const float*)d_in[3];
  const float* mask   = (const float*)d_in[4];
  const float* wq     = (const float*)d_in[5];
  const float* bq     = (const float*)d_in[6];
  const float* wkv    = (const float*)d_in[7];
  const float* bkv    = (const float*)d_in[8];
  const float* wqp    = (const float*)d_in[9];
  const float* bqp    = (const float*)d_in[10];
  const float* wkvp   = (const float*)d_in[11];
  const float* bkvp   = (const float*)d_in[12];
  const float* wb     = (const float*)d_in[13];
  const float* bb     = (const float*)d_in[14];
  const float* head_w = (const float*)d_in[15];
  const float* wout   = (const float*)d_in[16];
  const float* bout   = (const float*)d_in[17];
  float* out = (float*)d_out;

  // workspace layout (floats; all bases 16-float aligned)
  float* ws = (float*)d_ws;
  float* proj_buf = ws;                                  // 1,179,648
  float* kc_buf   = proj_buf + (size_t)NN * PROJW;       // 196,608
  float* vc_buf   = kc_buf + (size_t)HH * 16 * NN;       // 196,608
  float* kpc_buf  = vc_buf + (size_t)HH * 16 * NN;       // 147,456
  float* vpc_buf  = kpc_buf + (size_t)HH * 12 * NN;      // 294,912
  float* knc_buf  = vpc_buf + (size_t)HH * 24 * NN;      // 12,288
  float* qpts_buf = knc_buf + (size_t)HH * NN;           // 147,456
  float* qn_buf   = qpts_buf + (size_t)NN * QPR;         // 12,288
  float* wbt_buf  = qn_buf + NN * HH;                    // 1,536
  float* hw_buf   = wbt_buf + HH * CZ;                   // 16
  float* optb_buf = hw_buf + 16;                         // 294,912
  float* cat_buf  = optb_buf + (size_t)NN * HH * 24;     // 2,162,688
  __hip_bfloat16* A_buf =
      (__hip_bfloat16*)(cat_buf + (size_t)NN * DCAT);    // 12,582,912 bf16

  prep<<<dim3(1), dim3(256), 0, stream>>>(wb, head_w, wbt_buf, hw_buf);
  proj_all<<<dim3(NN / 8, 9), dim3(256), 0, stream>>>(
      s, wq, bq, wkv, bkv, wqp, bqp, wkvp, bkvp, proj_buf);
  ipa_transform<<<dim3(NN), dim3(256), 0, stream>>>(
      proj_buf, rot, trans, kc_buf, vc_buf, qpts_buf, kpc_buf, vpc_buf,
      qn_buf, knc_buf);
  bias_pass<<<dim3(8, NN), dim3(256), 0, stream>>>(z, wbt_buf, A_buf);
  ipa_attn<<<dim3(NN / 4, HH), dim3(256), 0, stream>>>(
      kc_buf, kpc_buf, knc_buf, vc_buf, vpc_buf, proj_buf, qpts_buf,
      qn_buf, bb, hw_buf, mask, A_buf, cat_buf, optb_buf);
  ipa_finish<<<dim3(NN), dim3(128), 0, stream>>>(optb_buf, rot, trans, cat_buf);
  opair_pass<<<dim3(NN), dim3(256), 0, stream>>>(z, A_buf, cat_buf);
  out_gemm<<<dim3(NN / 4, 3), dim3(256), 0, stream>>>(
      cat_buf, wout, bout, out);
}